// Round 1
// 2612.440 us; speedup vs baseline: 1.1445x; 1.1445x over previous
//
#include <hip/hip_runtime.h>
#include <hip/hip_bf16.h>
#include <math.h>

// FADiTBlockS2: b=4, nlat=128, nlon=256, dim=256, H=8, DH=64, BNECK=128, NK=32
// Round 5: k_ffn2 (45% of runtime, MfmaUtil 4%, occ 24%) replaced by k_ffn3:
//  - LN fully in registers per wave (A-frag rows are l15; stats via shfl_xor 16/32)
//  - no __syncthreads at all: hs staging is per-wave private rows; intra-wave
//    ordering via s_waitcnt lgkmcnt(0) + sched_barrier(0x7F) (blocks DS only,
//    lets VMEM weight prefetch cross phase boundaries)
//  - LDS 57856 -> 9216 B (2 -> 3+ blocks/CU), launch_bounds(256,3)
//  - exp2-based GELU (identity-exact), direct register epilogue (64B stores)

#define B_ 4
#define NLAT 128
#define NLON 256
#define NTOK (B_*NLAT*NLON)   // 131072

typedef __hip_bfloat16 bf16;
typedef unsigned short u16;
typedef __attribute__((ext_vector_type(8))) short short8;
typedef __attribute__((ext_vector_type(4))) float f32x4;

__device__ __forceinline__ float b2f(bf16 x){ return __bfloat162float(x); }
__device__ __forceinline__ bf16  f2b(float x){ return __float2bfloat16(x); }
__device__ __forceinline__ u16 f2bits(float x){
  bf16 h = __float2bfloat16(x); return *(u16*)&h;
}
__device__ __forceinline__ float bits2f(u16 u){
  union { unsigned int i; float f; } v; v.i = ((unsigned int)u) << 16; return v.f;
}
__device__ __forceinline__ float gelu_f(float x){
  float x3 = x*x*x;
  return 0.5f*x*(1.0f + tanhf(0.7978845608028654f*(x + 0.044715f*x3)));
}
// identity-exact fast gelu: tanh(t) = 1 - 2/(exp2(t*2/ln2)+1)
// gelu = 0.5x(1+tanh) = x - x/(e+1), e = 2^(t*2.885390...)
__device__ __forceinline__ float gelu_fast(float x){
  float t = 0.7978845608028654f*(x + 0.044715f*x*x*x);
  float e = __builtin_amdgcn_exp2f(t * 2.8853900817779268f);
  return x - x*__builtin_amdgcn_rcpf(e + 1.0f);
}
__device__ __forceinline__ float ldin(const void* p, size_t i, int flag){
  return flag ? b2f(((const bf16*)p)[i]) : ((const float*)p)[i];
}
__device__ __forceinline__ short4 pack4(float a, float b, float c, float d){
  short4 r; r.x = (short)f2bits(a); r.y = (short)f2bits(b);
  r.z = (short)f2bits(c); r.w = (short)f2bits(d); return r;
}
__device__ __forceinline__ short8 pack8(float a, float b, float c, float d,
                                        float e, float f, float g, float h){
  short8 r;
  r[0]=(short)f2bits(a); r[1]=(short)f2bits(b); r[2]=(short)f2bits(c); r[3]=(short)f2bits(d);
  r[4]=(short)f2bits(e); r[5]=(short)f2bits(f); r[6]=(short)f2bits(g); r[7]=(short)f2bits(h);
  return r;
}

// ---------------- dtype detection: lon_diff[1] == 2*pi/256 -----------------
__global__ void k_detect(const void* lon_diff, int* flag){
  const float c = 0.02454369260617026f;
  float asF = ((const float*)lon_diff)[1];
  float asB = b2f(((const bf16*)lon_diff)[1]);
  float ef = fabsf(asF - c), eb = fabsf(asB - c);
  if (!isfinite(ef)) ef = 1e30f;
  *flag = (eb < ef) ? 1 : 0;   // 1 = bf16 buffers, 0 = f32 buffers
}

__global__ __launch_bounds__(256) void k_cvt(const void* __restrict__ src,
                                             float* __restrict__ dst, int n,
                                             const int* __restrict__ flag){
  int f = *flag;
  for (int i = blockIdx.x*256 + threadIdx.x; i < n; i += gridDim.x*256)
    dst[i] = ldin(src, i, f);
}

// ------- pack weight [K][N] f32 -> fragment-order bf16 (ffn weights) -------
__global__ __launch_bounds__(256) void k_wprep(const float* __restrict__ W,
                                               u16* __restrict__ wf,
                                               int KS, int ldn, int total){
  int gid = blockIdx.x*256 + threadIdx.x;
  if (gid >= total) return;
  int j = gid & 7; int lane = (gid >> 3) & 63; int rest = gid >> 9;
  int ks = rest % KS; int nt = rest / KS;
  int k = ks*32 + (lane >> 4)*8 + j;
  int n = nt*16 + (lane & 15);
  wf[gid] = f2bits(W[(size_t)k*ldn + n]);
}

// ------- transposed bf16 copy: WT[n][k] = W[k][n] ---------------------------
__global__ __launch_bounds__(256) void k_wtrans(const float* __restrict__ W,
                                                u16* __restrict__ WT, int K, int N){
  int gid = blockIdx.x*256 + threadIdx.x;
  if (gid >= K*N) return;
  int k = gid % K, n = gid / K;
  WT[(size_t)n*K + k] = f2bits(W[(size_t)k*N + n]);
}

// ---------------- mod = scalar_cond @ adaLN_w + adaLN_b  (4 x 1536) --------
__global__ __launch_bounds__(256) void k_mod(const float* __restrict__ sc,
                                             const float* __restrict__ w,
                                             const float* __restrict__ bias,
                                             float* __restrict__ mod){
  int gid = blockIdx.x*256 + threadIdx.x;
  int s = gid / 1536, j = gid % 1536;
  float acc = bias[j];
  for (int c = 0; c < 256; ++c) acc += sc[s*256+c] * w[c*1536+j];
  mod[gid] = acc;
}

// ---------------- lw = cos(lat)/mean(cos(lat)) -----------------------------
__global__ __launch_bounds__(128) void k_lw(const float* __restrict__ lat,
                                            float* __restrict__ lw){
  __shared__ float red[128];
  int i = threadIdx.x;
  float cv = cosf(lat[i]);
  red[i] = cv; __syncthreads();
  for (int s = 64; s > 0; s >>= 1){ if (i < s) red[i] += red[i+s]; __syncthreads(); }
  float mean = red[0] * (1.0f/128.0f);
  lw[i] = cv / mean;
}

// ------- um = LN(u)*(1+sc_msa)+sh_msa : 64 tokens/block, coalesced ---------
__global__ __launch_bounds__(256) void k_um2(const void* __restrict__ u,
                                             const float* __restrict__ mod,
                                             u16* __restrict__ um,
                                             const int* __restrict__ flag){
  __shared__ u16 tile[64][264];
  __shared__ float r1[64][4], r2[64][4], mv[64], rs[64];
  __shared__ float ssh[256], ssc[256];
  int f = *flag; int tid = threadIdx.x;
  int t0 = blockIdx.x*64; int b = t0 >> 15;
  ssh[tid] = mod[b*1536 + tid];
  ssc[tid] = mod[b*1536 + 256 + tid];
  // phase 1: coalesced load -> bf16 tile
  for (int it = 0; it < 16; ++it){
    int idx = it*256 + tid;       // 4096 vec4 groups
    int tok = idx >> 6, c4 = idx & 63;
    short4 v4;
    if (f){
      v4 = *(const short4*)((const bf16*)u + ((size_t)(t0+tok))*256 + c4*4);
    } else {
      float4 fv = ((const float4*)u)[((size_t)(t0+tok))*64 + c4];
      v4 = pack4(fv.x, fv.y, fv.z, fv.w);
    }
    *(short4*)&tile[tok][c4*4] = v4;
  }
  __syncthreads();
  // phase 2: stats (4 threads per token)
  {
    int tok = tid >> 2, part = tid & 3;
    float s1 = 0.f, s2 = 0.f;
    for (int c4 = 0; c4 < 16; ++c4){
      short4 v4 = *(const short4*)&tile[tok][part*64 + c4*4];
      float a = bits2f((u16)v4.x), bb = bits2f((u16)v4.y),
            c = bits2f((u16)v4.z), d = bits2f((u16)v4.w);
      s1 += a+bb+c+d; s2 += a*a+bb*bb+c*c+d*d;
    }
    r1[tok][part] = s1; r2[tok][part] = s2;
  }
  __syncthreads();
  if ((tid & 3) == 0){
    int tok = tid >> 2;
    float a1 = r1[tok][0]+r1[tok][1]+r1[tok][2]+r1[tok][3];
    float a2 = r2[tok][0]+r2[tok][1]+r2[tok][2]+r2[tok][3];
    float mean = a1*(1.0f/256.0f);
    float var = a2*(1.0f/256.0f) - mean*mean;
    mv[tok] = mean; rs[tok] = rsqrtf(var + 1e-5f);
  }
  __syncthreads();
  // phase 3: modulate + coalesced store
  for (int it = 0; it < 16; ++it){
    int idx = it*256 + tid;
    int tok = idx >> 6, c4 = idx & 63;
    float mean = mv[tok], rstd = rs[tok];
    short4 v4 = *(const short4*)&tile[tok][c4*4];
    float y[4]; u16 raw[4] = {(u16)v4.x,(u16)v4.y,(u16)v4.z,(u16)v4.w};
    #pragma unroll
    for (int p = 0; p < 4; ++p){
      int c = c4*4 + p;
      y[p] = (bits2f(raw[p]) - mean)*rstd*(1.0f + ssc[c]) + ssh[c];
    }
    *(short4*)(um + ((size_t)(t0+tok))*256 + c4*4) = pack4(y[0],y[1],y[2],y[3]);
  }
}

// ---------------- redx[b,l,c] = (1/128) * sum_i um[b,i,l,c]*lw[i] ----------
__global__ __launch_bounds__(256) void k_redx(const u16* __restrict__ um,
                                              const float* __restrict__ lw,
                                              float* __restrict__ redx){
  __shared__ float lws[128];
  int tid = threadIdx.x;
  if (tid < 128) lws[tid] = lw[tid];
  __syncthreads();
  int gid = blockIdx.x*256 + tid;
  int c = gid & 255; int l = (gid >> 8) & 255; int b = gid >> 16;
  float acc = 0.0f;
  for (int i = 0; i < 128; ++i)
    acc += bits2f(um[(((size_t)(b*128 + i)*256 + l)*256) + c]) * lws[i];
  redx[gid] = acc * (1.0f/128.0f);
}

__global__ __launch_bounds__(256) void k_redy(const u16* __restrict__ um,
                                              float* __restrict__ redy){
  int gid = blockIdx.x*256 + threadIdx.x;
  int c = gid & 255; int i = (gid >> 8) & 127; int b = gid >> 15;
  float acc = 0.0f;
  for (int l = 0; l < 256; ++l)
    acc += bits2f(um[(((size_t)(b*128 + i)*256 + l)*256) + c]);
  redy[gid] = acc * (1.0f/256.0f);
}

// ---------------- generic row GEMM (tiny bottleneck chain) -----------------
__global__ __launch_bounds__(256) void gemm_row(const float* __restrict__ A,
                                                const float* __restrict__ W,
                                                const float* __restrict__ bias,
                                                float* __restrict__ C,
                                                int K, int N, int act){
  __shared__ float As[256];
  int r = blockIdx.x; int tid = threadIdx.x;
  for (int k = tid; k < K; k += 256) As[k] = A[(size_t)r*K + k];
  __syncthreads();
  for (int n = tid; n < N; n += 256){
    float acc = bias ? bias[n] : 0.0f;
    for (int k = 0; k < K; ++k) acc += As[k] * W[(size_t)k*N + n];
    if (act == 1) acc = gelu_f(acc);
    C[(size_t)r*N + n] = acc;
  }
}

// ---------------- radial[h,i,j] ---------------------------------------------
__global__ __launch_bounds__(256) void k_radial(const float* __restrict__ d,
                                                const float* __restrict__ w,
                                                float* __restrict__ rad, int n){
  int gid = blockIdx.x*256 + threadIdx.x;
  int nn = n*n;
  int h = gid / nn; int rem = gid % nn;
  float dv = d[rem];
  float safe = fmaxf(dv, 1e-6f);
  float acc = 0.0f;
  for (int k = 0; k < 32; ++k){
    float nk = (float)(k+1);
    float basis = (dv > 1e-6f) ? (sinf(dv*nk)/safe) : nk;
    acc += basis * w[k*8 + h];
  }
  rad[gid] = acc;
}

// ---------------- attention weights -> bf16 rows [bh][i][j] ----------------
__global__ __launch_bounds__(256) void k_attn(const float* __restrict__ qk,
                                              const float* __restrict__ rad,
                                              u16* __restrict__ kout, int n){
  extern __shared__ float sm[];
  float* qs = sm; float* red = sm + 64;
  int j = threadIdx.x;
  int bid = blockIdx.x; int i = bid % n; int h = (bid / n) & 7; int b = bid / (n*8);
  if (j < 64) qs[j] = qk[((size_t)(b*n + i))*1024 + h*64 + j];
  __syncthreads();
  float dot = 0.0f;
  const float* krow = qk + ((size_t)(b*n + j))*1024 + 512 + h*64;
  for (int d0 = 0; d0 < 64; ++d0) dot += qs[d0]*krow[d0];
  float s = dot * rad[((size_t)(h*n + i))*n + j];
  red[j] = s; __syncthreads();
  for (int st = n>>1; st > 0; st >>= 1){ if (j < st) red[j] = fmaxf(red[j], red[j+st]); __syncthreads(); }
  float mx = red[0]; __syncthreads();
  float e = expf(s - mx);
  red[j] = e; __syncthreads();
  for (int st = n>>1; st > 0; st >>= 1){ if (j < st) red[j] += red[j+st]; __syncthreads(); }
  float sum = red[0];
  kout[(size_t)bid*n + j] = f2bits(e / sum);
}

// ======== k_v2: per-b v-proj, C^T form. M=512 hc, N=64 tokens, K=256 =======
__global__ __launch_bounds__(256) void k_v2(const u16* __restrict__ um,
                                            const u16* __restrict__ WvT,
                                            u16* __restrict__ vT, int b){
  int tid = threadIdx.x;
  int wave = tid>>6, lane = tid&63, quad = lane>>4, l15 = lane&15;
  int t0 = blockIdx.x*64;
  const u16* umb = um + ((size_t)b*32768 + t0)*256;
  f32x4 acc[8][4];
  #pragma unroll
  for (int mt = 0; mt < 8; ++mt)
    #pragma unroll
    for (int nt = 0; nt < 4; ++nt) acc[mt][nt] = (f32x4){0.f,0.f,0.f,0.f};
  for (int ks = 0; ks < 8; ++ks){
    short8 bfr[4];
    #pragma unroll
    for (int nt = 0; nt < 4; ++nt)
      bfr[nt] = *(const short8*)(umb + (size_t)(nt*16 + l15)*256 + ks*32 + quad*8);
    #pragma unroll
    for (int mt = 0; mt < 8; ++mt){
      short8 a = *(const short8*)(WvT + (size_t)((wave*8+mt)*16 + l15)*256 + ks*32 + quad*8);
      #pragma unroll
      for (int nt = 0; nt < 4; ++nt)
        acc[mt][nt] = __builtin_amdgcn_mfma_f32_16x16x32_bf16(a, bfr[nt], acc[mt][nt], 0, 0, 0);
    }
  }
  #pragma unroll
  for (int mt = 0; mt < 8; ++mt){
    int hc0 = (wave*8+mt)*16 + quad*4;
    int h = hc0 >> 6, c0 = hc0 & 63;
    #pragma unroll
    for (int nt = 0; nt < 4; ++nt){
      int tok = t0 + nt*16 + l15;
      *(short4*)(vT + (size_t)h*2097152 + (size_t)tok*64 + c0)
        = pack4(acc[mt][nt][0], acc[mt][nt][1], acc[mt][nt][2], acc[mt][nt][3]);
    }
  }
}

// ======== k_phi1b: C^T. M=(c,m) 16384, N=i 128, K=j 128 ====================
// A = v gathers (8x u16, stride 32KB, L2), B = ky bf16 rows. Out: phi[h][i][c*256+m]
__global__ __launch_bounds__(256) void k_phi1b(const u16* __restrict__ kyb,
                                               const u16* __restrict__ vT,
                                               u16* __restrict__ phi, int b){
  int tid = threadIdx.x;
  int wave = tid>>6, lane = tid&63, quad = lane>>4, l15 = lane&15;
  int bid = blockIdx.x; int mblk = bid & 63, h = bid >> 6;
  int m0 = mblk*256;
  const u16* vTh = vT + (size_t)h*2097152;
  const u16* kyh = kyb + (size_t)(b*8+h)*16384;
  f32x4 acc[4][8];
  #pragma unroll
  for (int mt = 0; mt < 4; ++mt)
    #pragma unroll
    for (int nt = 0; nt < 8; ++nt) acc[mt][nt] = (f32x4){0.f,0.f,0.f,0.f};
  for (int ks = 0; ks < 4; ++ks){
    short8 bfr[8];
    #pragma unroll
    for (int nt = 0; nt < 8; ++nt)
      bfr[nt] = *(const short8*)(kyh + (size_t)(nt*16 + l15)*128 + ks*32 + quad*8);
    #pragma unroll
    for (int mt = 0; mt < 4; ++mt){
      int cm = m0 + (wave*4+mt)*16 + l15;
      int c = cm >> 8, m = cm & 255;
      const u16* gp = vTh + ((size_t)(ks*32 + quad*8)*256 + m)*64 + c;
      short8 a;
      #pragma unroll
      for (int jj = 0; jj < 8; ++jj) ((u16*)&a)[jj] = gp[(size_t)jj*16384];
      #pragma unroll
      for (int nt = 0; nt < 8; ++nt)
        acc[mt][nt] = __builtin_amdgcn_mfma_f32_16x16x32_bf16(a, bfr[nt], acc[mt][nt], 0, 0, 0);
    }
  }
  #pragma unroll
  for (int mt = 0; mt < 4; ++mt){
    int cmr = m0 + (wave*4+mt)*16 + quad*4;
    #pragma unroll
    for (int nt = 0; nt < 8; ++nt){
      int i = nt*16 + l15;
      *(short4*)(phi + (size_t)h*2097152 + (size_t)i*16384 + cmr)
        = pack4(acc[mt][nt][0], acc[mt][nt][1], acc[mt][nt][2], acc[mt][nt][3]);
    }
  }
}

// ======== k_phi2b: M=(i,c) 8192, N=l 256, K=m 256 ==========================
// A = phi rows (m-fastest), B = kx bf16 rows. Out: OUTt[h][l][i*64+c]
__global__ __launch_bounds__(256) void k_phi2b(const u16* __restrict__ kxb,
                                               const u16* __restrict__ phi,
                                               u16* __restrict__ OUTt, int b){
  int tid = threadIdx.x;
  int wave = tid>>6, lane = tid&63, quad = lane>>4, l15 = lane&15;
  int bid = blockIdx.x; int mblk = bid & 63, h = bid >> 6;
  int m0 = mblk*128;
  int mhalf = (wave&1)*4, nhalf = (wave>>1)*8;
  const u16* ph = phi + (size_t)h*2097152;
  const u16* kxh = kxb + (size_t)(b*8+h)*65536;
  f32x4 acc[4][8];
  #pragma unroll
  for (int mt = 0; mt < 4; ++mt)
    #pragma unroll
    for (int nt = 0; nt < 8; ++nt) acc[mt][nt] = (f32x4){0.f,0.f,0.f,0.f};
  for (int ks = 0; ks < 8; ++ks){
    short8 bfr[8];
    #pragma unroll
    for (int nt = 0; nt < 8; ++nt)
      bfr[nt] = *(const short8*)(kxh + (size_t)((nhalf+nt)*16 + l15)*256 + ks*32 + quad*8);
    #pragma unroll
    for (int mt = 0; mt < 4; ++mt){
      int m2 = m0 + (mhalf+mt)*16 + l15;
      short8 a = *(const short8*)(ph + (size_t)m2*256 + ks*32 + quad*8);
      #pragma unroll
      for (int nt = 0; nt < 8; ++nt)
        acc[mt][nt] = __builtin_amdgcn_mfma_f32_16x16x32_bf16(a, bfr[nt], acc[mt][nt], 0, 0, 0);
    }
  }
  #pragma unroll
  for (int mt = 0; mt < 4; ++mt){
    int m2r = m0 + (mhalf+mt)*16 + quad*4;
    #pragma unroll
    for (int nt = 0; nt < 8; ++nt){
      int l = (nhalf+nt)*16 + l15;
      *(short4*)(OUTt + (size_t)h*2097152 + (size_t)l*8192 + m2r)
        = pack4(acc[mt][nt][0], acc[mt][nt][1], acc[mt][nt][2], acc[mt][nt][3]);
    }
  }
}

// ======== k_gnb: GroupNorm over 64-c groups, coalesced ======================
// OUTt[h][l][i*64+c] -> gn[(i*256+l)][h*64+c]
__global__ __launch_bounds__(256) void k_gnb(const u16* __restrict__ OUTt,
                                             u16* __restrict__ gn){
  int tid = threadIdx.x;
  int bid = blockIdx.x; int l = bid & 255, h = bid >> 8;
  int i = tid >> 1, half = tid & 1;
  const u16* src = OUTt + (size_t)h*2097152 + (size_t)l*8192 + i*64 + half*32;
  float v[32]; float s1 = 0.f, s2 = 0.f;
  #pragma unroll
  for (int c4 = 0; c4 < 8; ++c4){
    short4 v4 = *(const short4*)(src + c4*4);
    v[c4*4+0] = bits2f((u16)v4.x); v[c4*4+1] = bits2f((u16)v4.y);
    v[c4*4+2] = bits2f((u16)v4.z); v[c4*4+3] = bits2f((u16)v4.w);
  }
  #pragma unroll
  for (int c = 0; c < 32; ++c){ s1 += v[c]; s2 += v[c]*v[c]; }
  s1 += __shfl_xor(s1, 1); s2 += __shfl_xor(s2, 1);
  float mean = s1*(1.0f/64.0f);
  float var = s2*(1.0f/64.0f) - mean*mean;
  float rstd = rsqrtf(var + 1e-6f);
  u16* dst = gn + ((size_t)(i*256 + l))*512 + h*64 + half*32;
  #pragma unroll
  for (int c4 = 0; c4 < 8; ++c4)
    *(short4*)(dst + c4*4) = pack4((v[c4*4+0]-mean)*rstd, (v[c4*4+1]-mean)*rstd,
                                   (v[c4*4+2]-mean)*rstd, (v[c4*4+3]-mean)*rstd);
}

// ======== k_mergeb: C^T. M=d 256, N=128 tokens, K=512 ======================
__global__ __launch_bounds__(256) void k_mergeb(const u16* __restrict__ gn,
                                                const u16* __restrict__ WmT,
                                                const float* __restrict__ biasm,
                                                const float* __restrict__ mod,
                                                const void* __restrict__ u,
                                                void* __restrict__ outv,
                                                const int* __restrict__ flag, int b){
  __shared__ float smg[256], sbb[256];
  int f = *flag;
  int tid = threadIdx.x;
  smg[tid] = mod[b*1536 + 512 + tid];
  sbb[tid] = biasm[tid];
  __syncthreads();
  int wave = tid>>6, lane = tid&63, quad = lane>>4, l15 = lane&15;
  int t0 = blockIdx.x*128;
  int nt0 = wave*2;
  f32x4 acc[16][2];
  #pragma unroll
  for (int mt = 0; mt < 16; ++mt){ acc[mt][0] = (f32x4){0.f,0.f,0.f,0.f}; acc[mt][1] = (f32x4){0.f,0.f,0.f,0.f}; }
  for (int ks = 0; ks < 16; ++ks){
    short8 bfr[2];
    #pragma unroll
    for (int nti = 0; nti < 2; ++nti){
      int tok = t0 + (nt0+nti)*16 + l15;
      bfr[nti] = *(const short8*)(gn + (size_t)tok*512 + ks*32 + quad*8);
    }
    #pragma unroll
    for (int mt = 0; mt < 16; ++mt){
      short8 a = *(const short8*)(WmT + (size_t)(mt*16 + l15)*512 + ks*32 + quad*8);
      #pragma unroll
      for (int nti = 0; nti < 2; ++nti)
        acc[mt][nti] = __builtin_amdgcn_mfma_f32_16x16x32_bf16(a, bfr[nti], acc[mt][nti], 0, 0, 0);
    }
  }
  #pragma unroll
  for (int mt = 0; mt < 16; ++mt){
    int d0 = mt*16 + quad*4;
    #pragma unroll
    for (int nti = 0; nti < 2; ++nti){
      int tok = t0 + (nt0+nti)*16 + l15;
      size_t o = ((size_t)b*32768 + tok)*256 + d0;
      float r0,r1,r2,r3;
      if (f){
        short4 rv = *(const short4*)((const bf16*)u + o);
        r0 = bits2f((u16)rv.x); r1 = bits2f((u16)rv.y); r2 = bits2f((u16)rv.z); r3 = bits2f((u16)rv.w);
      } else {
        float4 rv = *(const float4*)((const float*)u + o);
        r0 = rv.x; r1 = rv.y; r2 = rv.z; r3 = rv.w;
      }
      float y0 = r0 + smg[d0+0]*(acc[mt][nti][0] + sbb[d0+0]);
      float y1 = r1 + smg[d0+1]*(acc[mt][nti][1] + sbb[d0+1]);
      float y2 = r2 + smg[d0+2]*(acc[mt][nti][2] + sbb[d0+2]);
      float y3 = r3 + smg[d0+3]*(acc[mt][nti][3] + sbb[d0+3]);
      if (f) *(short4*)((bf16*)outv + o) = pack4(y0,y1,y2,y3);
      else   *(float4*)((float*)outv + o) = (float4){y0,y1,y2,y3};
    }
  }
}

// ======== k_ffn3: barrier-free per-wave FFN (LN + 256->1024 gelu ->256) ====
// Each wave owns 16 tokens end-to-end. No __syncthreads anywhere.
//  - LN in registers: A-frag row = l15, k = ks*32+quad*8+j; row stats via
//    shfl_xor(16/32) over the 4 lanes sharing l15.
//  - hc loop over 16 chunks of 64 hidden: gemm1 (4 nt) -> gelu -> transposed
//    scalar writes into per-wave hs rows -> b128 A2-frag reads -> gemm2.
//  - intra-wave LDS ordering: s_waitcnt lgkmcnt(0) + sched_barrier(0x7F)
//    (blocks DS motion only; VMEM weight prefetch may cross).
//  - epilogue: direct scalar stores (16-lane x 4B = 64B segments, f32 path).
__global__ __launch_bounds__(256, 3) void k_ffn3(
    const float* __restrict__ mod,
    const u16* __restrict__ w1f,
    const float* __restrict__ b1c,
    const u16* __restrict__ w2f,
    const float* __restrict__ b2c,
    void* __restrict__ outv,
    const int* __restrict__ flag){
  __shared__ __align__(16) u16 hs[64][72];   // per-wave 16 rows x 64 cols (+8 pad)
  int f = *flag;
  int tid = threadIdx.x;
  int wave = tid>>6, lane = tid&63, quad = lane>>4, l15 = lane&15;
  int mrow = wave*16;
  int t0 = blockIdx.x*64;
  int bb = t0 >> 15;
  const float* modp = mod + bb*1536;
  size_t rowbase = ((size_t)(t0 + mrow + l15))*256;

  // ---- LN in registers: load A-frags, row stats via cross-quad shuffles ----
  short8 afr[8];
  float s1 = 0.f, s2 = 0.f;
  #pragma unroll
  for (int ks = 0; ks < 8; ++ks){
    int c0 = ks*32 + quad*8;
    float v0,v1,v2,v3,v4,v5,v6,v7;
    if (f){
      short8 r = *(const short8*)((const bf16*)outv + rowbase + c0);
      afr[ks] = r;
      v0 = bits2f((u16)r[0]); v1 = bits2f((u16)r[1]); v2 = bits2f((u16)r[2]); v3 = bits2f((u16)r[3]);
      v4 = bits2f((u16)r[4]); v5 = bits2f((u16)r[5]); v6 = bits2f((u16)r[6]); v7 = bits2f((u16)r[7]);
    } else {
      float4 fa = *(const float4*)((const float*)outv + rowbase + c0);
      float4 fb = *(const float4*)((const float*)outv + rowbase + c0 + 4);
      v0=fa.x; v1=fa.y; v2=fa.z; v3=fa.w; v4=fb.x; v5=fb.y; v6=fb.z; v7=fb.w;
      afr[ks] = pack8(v0,v1,v2,v3,v4,v5,v6,v7);
    }
    s1 += v0+v1+v2+v3+v4+v5+v6+v7;
    s2 += v0*v0+v1*v1+v2*v2+v3*v3+v4*v4+v5*v5+v6*v6+v7*v7;
  }
  s1 += __shfl_xor(s1, 16); s1 += __shfl_xor(s1, 32);
  s2 += __shfl_xor(s2, 16); s2 += __shfl_xor(s2, 32);
  float mean = s1*(1.0f/256.0f);
  float var = s2*(1.0f/256.0f) - mean*mean;
  float rstd = rsqrtf(var + 1e-5f);
  // ---- modulate in registers: y = (v-mean)*rstd*(1+sc)+sh ----
  #pragma unroll
  for (int ks = 0; ks < 8; ++ks){
    int c0 = ks*32 + quad*8;
    float4 sh0 = *(const float4*)&modp[768 + c0];
    float4 sh1 = *(const float4*)&modp[768 + c0 + 4];
    float4 sc0 = *(const float4*)&modp[1024 + c0];
    float4 sc1 = *(const float4*)&modp[1024 + c0 + 4];
    short8 r = afr[ks];
    float y0 = (bits2f((u16)r[0]) - mean)*rstd*(1.0f+sc0.x) + sh0.x;
    float y1 = (bits2f((u16)r[1]) - mean)*rstd*(1.0f+sc0.y) + sh0.y;
    float y2 = (bits2f((u16)r[2]) - mean)*rstd*(1.0f+sc0.z) + sh0.z;
    float y3 = (bits2f((u16)r[3]) - mean)*rstd*(1.0f+sc0.w) + sh0.w;
    float y4 = (bits2f((u16)r[4]) - mean)*rstd*(1.0f+sc1.x) + sh1.x;
    float y5 = (bits2f((u16)r[5]) - mean)*rstd*(1.0f+sc1.y) + sh1.y;
    float y6 = (bits2f((u16)r[6]) - mean)*rstd*(1.0f+sc1.z) + sh1.z;
    float y7 = (bits2f((u16)r[7]) - mean)*rstd*(1.0f+sc1.w) + sh1.w;
    afr[ks] = pack8(y0,y1,y2,y3,y4,y5,y6,y7);
  }

  // ---- main loop: 16 chunks of 64 hidden ----
  f32x4 acc2[16];
  #pragma unroll
  for (int nt = 0; nt < 16; ++nt) acc2[nt] = (f32x4){0.f,0.f,0.f,0.f};
  #pragma unroll 1
  for (int hcc = 0; hcc < 16; ++hcc){
    // gemm1: 16 tok x 64 hid, K=256
    f32x4 acc1[4];
    #pragma unroll
    for (int nt = 0; nt < 4; ++nt) acc1[nt] = (f32x4){0.f,0.f,0.f,0.f};
    #pragma unroll
    for (int ks = 0; ks < 8; ++ks){
      #pragma unroll
      for (int nt = 0; nt < 4; ++nt){
        short8 bfr = *(const short8*)&w1f[(((size_t)((hcc*4+nt)*8 + ks))*64 + lane)*8];
        acc1[nt] = __builtin_amdgcn_mfma_f32_16x16x32_bf16(afr[ks], bfr, acc1[nt], 0, 0, 0);
      }
    }
    // WAR guard: previous iteration's ds_reads stay above, this iteration's
    // ds_writes stay below (DS may not cross; VMEM/MFMA/VALU may).
    __builtin_amdgcn_sched_barrier(0x7F);
    // gelu + transposed scalar stores to this wave's private rows
    #pragma unroll
    for (int nt = 0; nt < 4; ++nt){
      int hid = nt*16 + l15;
      float b1 = b1c[hcc*64 + hid];
      #pragma unroll
      for (int r = 0; r < 4; ++r){
        hs[mrow + quad*4 + r][hid] = f2bits(gelu_fast(acc1[nt][r] + b1));
      }
    }
    // RAW guard: all writes complete before A2-frag reads issue
    asm volatile("s_waitcnt lgkmcnt(0)");
    __builtin_amdgcn_sched_barrier(0x7F);
    // gemm2: 16 tok x 256 out, K=64 for this chunk
    #pragma unroll
    for (int ks2 = 0; ks2 < 2; ++ks2){
      short8 a2 = *(const short8*)&hs[mrow + l15][ks2*32 + quad*8];
      #pragma unroll
      for (int nt = 0; nt < 16; ++nt){
        short8 bfr = *(const short8*)&w2f[(((size_t)(nt*32 + hcc*2 + ks2))*64 + lane)*8];
        acc2[nt] = __builtin_amdgcn_mfma_f32_16x16x32_bf16(a2, bfr, acc2[nt], 0, 0, 0);
      }
    }
  }

  // ---- epilogue: direct register stores, u2 = u1 + g*(y + b2), in place ----
  #pragma unroll
  for (int nt = 0; nt < 16; ++nt){
    int col = nt*16 + l15;
    float g = modp[1280 + col];
    float b2v = b2c[col];
    #pragma unroll
    for (int r = 0; r < 4; ++r){
      size_t o = ((size_t)(t0 + mrow + quad*4 + r))*256 + col;
      float resid = f ? bits2f(((const u16*)outv)[o]) : ((const float*)outv)[o];
      float y = resid + g*(acc2[nt][r] + b2v);
      if (f) ((u16*)outv)[o] = f2bits(y);
      else   ((float*)outv)[o] = y;
    }
  }
}

extern "C" void kernel_launch(void* const* d_in, const int* in_sizes, int n_in,
                              void* d_out, int out_size, void* d_ws, size_t ws_size,
                              hipStream_t stream){
  (void)n_in; (void)out_size; (void)ws_size;

  char* p = (char*)d_ws;
  auto alloc = [&](size_t bytes)->void*{
    void* r = (void*)p; p += (bytes + 255) & ~(size_t)255; return r;
  };

  int* flag = (int*)alloc(4);
  float* cin[28];
  cin[0] = nullptr;
  for (int i = 1; i < 28; ++i) cin[i] = (float*)alloc((size_t)in_sizes[i]*4);

  float* mod  = (float*)alloc((size_t)4*1536*4);
  float* lw   = (float*)alloc((size_t)128*4);
  float* redx = (float*)alloc((size_t)4*256*256*4);
  float* redy = (float*)alloc((size_t)4*128*256*4);
  float* tx   = (float*)alloc((size_t)4*256*256*4);
  float* hx   = (float*)alloc((size_t)4*256*256*4);
  float* uxb  = (float*)alloc((size_t)4*256*128*4);
  float* ty   = (float*)alloc((size_t)4*128*256*4);
  float* hy   = (float*)alloc((size_t)4*128*256*4);
  float* uyb  = (float*)alloc((size_t)4*128*128*4);
  float* qkx  = (float*)alloc((size_t)4*256*1024*4);
  float* qky  = (float*)alloc((size_t)4*128*1024*4);
  float* radx = (float*)alloc((size_t)8*256*256*4);
  float* rady = (float*)alloc((size_t)8*128*128*4);
  u16* kxb = (u16*)alloc((size_t)32*256*256*2);
  u16* kyb = (u16*)alloc((size_t)32*128*128*2);
  u16* w1f = (u16*)alloc((size_t)256*1024*2);
  u16* w2f = (u16*)alloc((size_t)1024*256*2);
  u16* WvT = (u16*)alloc((size_t)512*256*2);
  u16* WmT = (u16*)alloc((size_t)256*512*2);
  u16* um    = (u16*)alloc((size_t)NTOK*256*2);        // 67 MB
  u16* slotV = (u16*)alloc((size_t)8*2097152*2);       // 33.5 MB
  u16* slotP = (u16*)alloc((size_t)8*2097152*2);       // 33.5 MB

  const void* u = d_in[0];

  k_detect<<<1, 1, 0, stream>>>(d_in[3], flag);
  for (int i = 1; i < 28; ++i){
    int n = in_sizes[i];
    int blocks = (n + 255)/256; if (blocks > 1024) blocks = 1024;
    k_cvt<<<blocks, 256, 0, stream>>>(d_in[i], cin[i], n, flag);
  }
  k_wprep<<<1024, 256, 0, stream>>>(cin[24], w1f, 8, 1024, 256*1024);
  k_wprep<<<1024, 256, 0, stream>>>(cin[26], w2f, 32, 256, 1024*256);
  k_wtrans<<<512, 256, 0, stream>>>(cin[7],  WvT, 256, 512);   // to_v_w
  k_wtrans<<<512, 256, 0, stream>>>(cin[22], WmT, 512, 256);   // merge_w

  k_mod<<<24, 256, 0, stream>>>(cin[4], cin[5], cin[6], mod);
  k_lw<<<1, 128, 0, stream>>>(cin[1], lw);
  k_um2<<<NTOK/64, 256, 0, stream>>>(u, mod, um, flag);
  k_redx<<<1024, 256, 0, stream>>>(um, lw, redx);
  k_redy<<<512, 256, 0, stream>>>(um, redy);
  gemm_row<<<1024, 256, 0, stream>>>(redx, cin[8],  nullptr, tx,  256, 256, 0);
  gemm_row<<<1024, 256, 0, stream>>>(tx,   cin[9],  cin[10], hx,  256, 256, 1);
  gemm_row<<<1024, 256, 0, stream>>>(hx,   cin[11], cin[12], uxb, 256, 128, 0);
  gemm_row<<<1024, 256, 0, stream>>>(uxb,  cin[18], nullptr, qkx, 128, 1024, 0);
  gemm_row<<<512, 256, 0, stream>>>(redy, cin[13], nullptr, ty,  256, 256, 0);
  gemm_row<<<512, 256, 0, stream>>>(ty,   cin[14], cin[15], hy,  256, 256, 1);
  gemm_row<<<512, 256, 0, stream>>>(hy,   cin[16], cin[17], uyb, 256, 128, 0);
  gemm_row<<<512, 256, 0, stream>>>(uyb,  cin[19], nullptr, qky, 128, 1024, 0);
  k_radial<<<(8*256*256)/256, 256, 0, stream>>>(cin[3], cin[20], radx, 256);
  k_radial<<<(8*128*128)/256, 256, 0, stream>>>(cin[2], cin[21], rady, 128);
  k_attn<<<4*8*256, 256, (64+256)*4, stream>>>(qkx, radx, kxb, 256);
  k_attn<<<4*8*128, 128, (64+128)*4, stream>>>(qky, rady, kyb, 128);

  for (int b = 0; b < 4; ++b){
    u16* vTb  = slotV;   // vT[h][tok][c]
    u16* phb  = slotP;   // phi[h][i][c*256+m]
    u16* outt = slotV;   // OUTt[h][l][i*64+c]  (vT dead)
    u16* gnb  = slotP;   // gn[tok][h*64+c]     (phi dead)
    k_v2    <<<512, 256, 0, stream>>>(um, WvT, vTb, b);
    k_phi1b <<<512, 256, 0, stream>>>(kyb, vTb, phb, b);
    k_phi2b <<<512, 256, 0, stream>>>(kxb, phb, outt, b);
    k_gnb   <<<2048, 256, 0, stream>>>(outt, gnb);
    k_mergeb<<<256, 256, 0, stream>>>(gnb, WmT, cin[23], mod, u, d_out, flag, b);
  }
  k_ffn3<<<NTOK/64, 256, 0, stream>>>(mod, w1f, cin[25], w2f, cin[27], d_out, flag);
}

// Round 2
// 1984.082 us; speedup vs baseline: 1.5069x; 1.3167x over previous
//
#include <hip/hip_runtime.h>
#include <hip/hip_bf16.h>
#include <math.h>

// FADiTBlockS2: b=4, nlat=128, nlon=256, dim=256, H=8, DH=64, BNECK=128, NK=32
// Round 6: k_ffn3 (972us, MfmaUtil 5.6%) was latency-serial on per-wave flat
// weight loads (~850 cyc/load, no MLP). k_ffn4 = canonical LDS double-buffered
// weight staging via global_load_lds (16B), shared across the block's 4 waves:
//   - 32 chunks of 32 hidden; per chunk 16KB w1 + 16KB w2, both contiguous
//     (w2f re-laid-out by k_wprep2 to [ksAll][nt][lane][8])
//   - 2-phase pipeline: STAGE(c+1) -> compute(c) -> __syncthreads per chunk
//   - B-operands via conflict-free linear ds_read_b128; LDS 70.6KB -> 2 blk/CU
//   - LN in registers as in ffn3; hs RAW guard: lgkmcnt(0)+sched_barrier(0)

#define B_ 4
#define NLAT 128
#define NLON 256
#define NTOK (B_*NLAT*NLON)   // 131072

typedef __hip_bfloat16 bf16;
typedef unsigned short u16;
typedef __attribute__((ext_vector_type(8))) short short8;
typedef __attribute__((ext_vector_type(4))) float f32x4;

__device__ __forceinline__ float b2f(bf16 x){ return __bfloat162float(x); }
__device__ __forceinline__ bf16  f2b(float x){ return __float2bfloat16(x); }
__device__ __forceinline__ u16 f2bits(float x){
  bf16 h = __float2bfloat16(x); return *(u16*)&h;
}
__device__ __forceinline__ float bits2f(u16 u){
  union { unsigned int i; float f; } v; v.i = ((unsigned int)u) << 16; return v.f;
}
__device__ __forceinline__ float gelu_f(float x){
  float x3 = x*x*x;
  return 0.5f*x*(1.0f + tanhf(0.7978845608028654f*(x + 0.044715f*x3)));
}
// identity-exact fast gelu: tanh(t) = 1 - 2/(exp2(t*2/ln2)+1)
__device__ __forceinline__ float gelu_fast(float x){
  float t = 0.7978845608028654f*(x + 0.044715f*x*x*x);
  float e = __builtin_amdgcn_exp2f(t * 2.8853900817779268f);
  return x - x*__builtin_amdgcn_rcpf(e + 1.0f);
}
__device__ __forceinline__ float ldin(const void* p, size_t i, int flag){
  return flag ? b2f(((const bf16*)p)[i]) : ((const float*)p)[i];
}
__device__ __forceinline__ short4 pack4(float a, float b, float c, float d){
  short4 r; r.x = (short)f2bits(a); r.y = (short)f2bits(b);
  r.z = (short)f2bits(c); r.w = (short)f2bits(d); return r;
}
__device__ __forceinline__ short8 pack8(float a, float b, float c, float d,
                                        float e, float f, float g, float h){
  short8 r;
  r[0]=(short)f2bits(a); r[1]=(short)f2bits(b); r[2]=(short)f2bits(c); r[3]=(short)f2bits(d);
  r[4]=(short)f2bits(e); r[5]=(short)f2bits(f); r[6]=(short)f2bits(g); r[7]=(short)f2bits(h);
  return r;
}
// async global->LDS 16B: lds dest is wave-uniform base (+lane*16 by HW),
// global src is per-lane.
__device__ __forceinline__ void stage16(const u16* g, u16* l){
  __builtin_amdgcn_global_load_lds(
      (const __attribute__((address_space(1))) void*)g,
      (__attribute__((address_space(3))) void*)l, 16, 0, 0);
}

// ---------------- dtype detection: lon_diff[1] == 2*pi/256 -----------------
__global__ void k_detect(const void* lon_diff, int* flag){
  const float c = 0.02454369260617026f;
  float asF = ((const float*)lon_diff)[1];
  float asB = b2f(((const bf16*)lon_diff)[1]);
  float ef = fabsf(asF - c), eb = fabsf(asB - c);
  if (!isfinite(ef)) ef = 1e30f;
  *flag = (eb < ef) ? 1 : 0;   // 1 = bf16 buffers, 0 = f32 buffers
}

__global__ __launch_bounds__(256) void k_cvt(const void* __restrict__ src,
                                             float* __restrict__ dst, int n,
                                             const int* __restrict__ flag){
  int f = *flag;
  for (int i = blockIdx.x*256 + threadIdx.x; i < n; i += gridDim.x*256)
    dst[i] = ldin(src, i, f);
}

// ------- pack weight [K][N] f32 -> fragment-order bf16 ([nt][ks][lane][8]) -
__global__ __launch_bounds__(256) void k_wprep(const float* __restrict__ W,
                                               u16* __restrict__ wf,
                                               int KS, int ldn, int total){
  int gid = blockIdx.x*256 + threadIdx.x;
  if (gid >= total) return;
  int j = gid & 7; int lane = (gid >> 3) & 63; int rest = gid >> 9;
  int ks = rest % KS; int nt = rest / KS;
  int k = ks*32 + (lane >> 4)*8 + j;
  int n = nt*16 + (lane & 15);
  wf[gid] = f2bits(W[(size_t)k*ldn + n]);
}

// ------- w2 pack: [ksAll 0..31][nt 0..15][lane][8]; W2 is [1024][256] ------
// chunk c (K-rows c*32..c*32+31) occupies contiguous 16KB at c*16384 B.
__global__ __launch_bounds__(256) void k_wprep2(const float* __restrict__ W,
                                                u16* __restrict__ wf){
  int gid = blockIdx.x*256 + threadIdx.x;   // 262144 total
  int j = gid & 7; int lane = (gid >> 3) & 63; int rest = gid >> 9;
  int nt = rest & 15; int ksAll = rest >> 4;
  int k = ksAll*32 + (lane >> 4)*8 + j;
  int n = nt*16 + (lane & 15);
  wf[gid] = f2bits(W[(size_t)k*256 + n]);
}

// ------- transposed bf16 copy: WT[n][k] = W[k][n] ---------------------------
__global__ __launch_bounds__(256) void k_wtrans(const float* __restrict__ W,
                                                u16* __restrict__ WT, int K, int N){
  int gid = blockIdx.x*256 + threadIdx.x;
  if (gid >= K*N) return;
  int k = gid % K, n = gid / K;
  WT[(size_t)n*K + k] = f2bits(W[(size_t)k*N + n]);
}

// ---------------- mod = scalar_cond @ adaLN_w + adaLN_b  (4 x 1536) --------
__global__ __launch_bounds__(256) void k_mod(const float* __restrict__ sc,
                                             const float* __restrict__ w,
                                             const float* __restrict__ bias,
                                             float* __restrict__ mod){
  int gid = blockIdx.x*256 + threadIdx.x;
  int s = gid / 1536, j = gid % 1536;
  float acc = bias[j];
  for (int c = 0; c < 256; ++c) acc += sc[s*256+c] * w[c*1536+j];
  mod[gid] = acc;
}

// ---------------- lw = cos(lat)/mean(cos(lat)) -----------------------------
__global__ __launch_bounds__(128) void k_lw(const float* __restrict__ lat,
                                            float* __restrict__ lw){
  __shared__ float red[128];
  int i = threadIdx.x;
  float cv = cosf(lat[i]);
  red[i] = cv; __syncthreads();
  for (int s = 64; s > 0; s >>= 1){ if (i < s) red[i] += red[i+s]; __syncthreads(); }
  float mean = red[0] * (1.0f/128.0f);
  lw[i] = cv / mean;
}

// ------- um = LN(u)*(1+sc_msa)+sh_msa : 64 tokens/block, coalesced ---------
__global__ __launch_bounds__(256) void k_um2(const void* __restrict__ u,
                                             const float* __restrict__ mod,
                                             u16* __restrict__ um,
                                             const int* __restrict__ flag){
  __shared__ u16 tile[64][264];
  __shared__ float r1[64][4], r2[64][4], mv[64], rs[64];
  __shared__ float ssh[256], ssc[256];
  int f = *flag; int tid = threadIdx.x;
  int t0 = blockIdx.x*64; int b = t0 >> 15;
  ssh[tid] = mod[b*1536 + tid];
  ssc[tid] = mod[b*1536 + 256 + tid];
  // phase 1: coalesced load -> bf16 tile
  for (int it = 0; it < 16; ++it){
    int idx = it*256 + tid;       // 4096 vec4 groups
    int tok = idx >> 6, c4 = idx & 63;
    short4 v4;
    if (f){
      v4 = *(const short4*)((const bf16*)u + ((size_t)(t0+tok))*256 + c4*4);
    } else {
      float4 fv = ((const float4*)u)[((size_t)(t0+tok))*64 + c4];
      v4 = pack4(fv.x, fv.y, fv.z, fv.w);
    }
    *(short4*)&tile[tok][c4*4] = v4;
  }
  __syncthreads();
  // phase 2: stats (4 threads per token)
  {
    int tok = tid >> 2, part = tid & 3;
    float s1 = 0.f, s2 = 0.f;
    for (int c4 = 0; c4 < 16; ++c4){
      short4 v4 = *(const short4*)&tile[tok][part*64 + c4*4];
      float a = bits2f((u16)v4.x), bb = bits2f((u16)v4.y),
            c = bits2f((u16)v4.z), d = bits2f((u16)v4.w);
      s1 += a+bb+c+d; s2 += a*a+bb*bb+c*c+d*d;
    }
    r1[tok][part] = s1; r2[tok][part] = s2;
  }
  __syncthreads();
  if ((tid & 3) == 0){
    int tok = tid >> 2;
    float a1 = r1[tok][0]+r1[tok][1]+r1[tok][2]+r1[tok][3];
    float a2 = r2[tok][0]+r2[tok][1]+r2[tok][2]+r2[tok][3];
    float mean = a1*(1.0f/256.0f);
    float var = a2*(1.0f/256.0f) - mean*mean;
    mv[tok] = mean; rs[tok] = rsqrtf(var + 1e-5f);
  }
  __syncthreads();
  // phase 3: modulate + coalesced store
  for (int it = 0; it < 16; ++it){
    int idx = it*256 + tid;
    int tok = idx >> 6, c4 = idx & 63;
    float mean = mv[tok], rstd = rs[tok];
    short4 v4 = *(const short4*)&tile[tok][c4*4];
    float y[4]; u16 raw[4] = {(u16)v4.x,(u16)v4.y,(u16)v4.z,(u16)v4.w};
    #pragma unroll
    for (int p = 0; p < 4; ++p){
      int c = c4*4 + p;
      y[p] = (bits2f(raw[p]) - mean)*rstd*(1.0f + ssc[c]) + ssh[c];
    }
    *(short4*)(um + ((size_t)(t0+tok))*256 + c4*4) = pack4(y[0],y[1],y[2],y[3]);
  }
}

// ---------------- redx[b,l,c] = (1/128) * sum_i um[b,i,l,c]*lw[i] ----------
__global__ __launch_bounds__(256) void k_redx(const u16* __restrict__ um,
                                              const float* __restrict__ lw,
                                              float* __restrict__ redx){
  __shared__ float lws[128];
  int tid = threadIdx.x;
  if (tid < 128) lws[tid] = lw[tid];
  __syncthreads();
  int gid = blockIdx.x*256 + tid;
  int c = gid & 255; int l = (gid >> 8) & 255; int b = gid >> 16;
  float acc = 0.0f;
  for (int i = 0; i < 128; ++i)
    acc += bits2f(um[(((size_t)(b*128 + i)*256 + l)*256) + c]) * lws[i];
  redx[gid] = acc * (1.0f/128.0f);
}

__global__ __launch_bounds__(256) void k_redy(const u16* __restrict__ um,
                                              float* __restrict__ redy){
  int gid = blockIdx.x*256 + threadIdx.x;
  int c = gid & 255; int i = (gid >> 8) & 127; int b = gid >> 15;
  float acc = 0.0f;
  for (int l = 0; l < 256; ++l)
    acc += bits2f(um[(((size_t)(b*128 + i)*256 + l)*256) + c]);
  redy[gid] = acc * (1.0f/256.0f);
}

// ---------------- generic row GEMM (tiny bottleneck chain) -----------------
__global__ __launch_bounds__(256) void gemm_row(const float* __restrict__ A,
                                                const float* __restrict__ W,
                                                const float* __restrict__ bias,
                                                float* __restrict__ C,
                                                int K, int N, int act){
  __shared__ float As[256];
  int r = blockIdx.x; int tid = threadIdx.x;
  for (int k = tid; k < K; k += 256) As[k] = A[(size_t)r*K + k];
  __syncthreads();
  for (int n = tid; n < N; n += 256){
    float acc = bias ? bias[n] : 0.0f;
    for (int k = 0; k < K; ++k) acc += As[k] * W[(size_t)k*N + n];
    if (act == 1) acc = gelu_f(acc);
    C[(size_t)r*N + n] = acc;
  }
}

// ---------------- radial[h,i,j] ---------------------------------------------
__global__ __launch_bounds__(256) void k_radial(const float* __restrict__ d,
                                                const float* __restrict__ w,
                                                float* __restrict__ rad, int n){
  int gid = blockIdx.x*256 + threadIdx.x;
  int nn = n*n;
  int h = gid / nn; int rem = gid % nn;
  float dv = d[rem];
  float safe = fmaxf(dv, 1e-6f);
  float acc = 0.0f;
  for (int k = 0; k < 32; ++k){
    float nk = (float)(k+1);
    float basis = (dv > 1e-6f) ? (sinf(dv*nk)/safe) : nk;
    acc += basis * w[k*8 + h];
  }
  rad[gid] = acc;
}

// ---------------- attention weights -> bf16 rows [bh][i][j] ----------------
__global__ __launch_bounds__(256) void k_attn(const float* __restrict__ qk,
                                              const float* __restrict__ rad,
                                              u16* __restrict__ kout, int n){
  extern __shared__ float sm[];
  float* qs = sm; float* red = sm + 64;
  int j = threadIdx.x;
  int bid = blockIdx.x; int i = bid % n; int h = (bid / n) & 7; int b = bid / (n*8);
  if (j < 64) qs[j] = qk[((size_t)(b*n + i))*1024 + h*64 + j];
  __syncthreads();
  float dot = 0.0f;
  const float* krow = qk + ((size_t)(b*n + j))*1024 + 512 + h*64;
  for (int d0 = 0; d0 < 64; ++d0) dot += qs[d0]*krow[d0];
  float s = dot * rad[((size_t)(h*n + i))*n + j];
  red[j] = s; __syncthreads();
  for (int st = n>>1; st > 0; st >>= 1){ if (j < st) red[j] = fmaxf(red[j], red[j+st]); __syncthreads(); }
  float mx = red[0]; __syncthreads();
  float e = expf(s - mx);
  red[j] = e; __syncthreads();
  for (int st = n>>1; st > 0; st >>= 1){ if (j < st) red[j] += red[j+st]; __syncthreads(); }
  float sum = red[0];
  kout[(size_t)bid*n + j] = f2bits(e / sum);
}

// ======== k_v2: per-b v-proj, C^T form. M=512 hc, N=64 tokens, K=256 =======
__global__ __launch_bounds__(256) void k_v2(const u16* __restrict__ um,
                                            const u16* __restrict__ WvT,
                                            u16* __restrict__ vT, int b){
  int tid = threadIdx.x;
  int wave = tid>>6, lane = tid&63, quad = lane>>4, l15 = lane&15;
  int t0 = blockIdx.x*64;
  const u16* umb = um + ((size_t)b*32768 + t0)*256;
  f32x4 acc[8][4];
  #pragma unroll
  for (int mt = 0; mt < 8; ++mt)
    #pragma unroll
    for (int nt = 0; nt < 4; ++nt) acc[mt][nt] = (f32x4){0.f,0.f,0.f,0.f};
  for (int ks = 0; ks < 8; ++ks){
    short8 bfr[4];
    #pragma unroll
    for (int nt = 0; nt < 4; ++nt)
      bfr[nt] = *(const short8*)(umb + (size_t)(nt*16 + l15)*256 + ks*32 + quad*8);
    #pragma unroll
    for (int mt = 0; mt < 8; ++mt){
      short8 a = *(const short8*)(WvT + (size_t)((wave*8+mt)*16 + l15)*256 + ks*32 + quad*8);
      #pragma unroll
      for (int nt = 0; nt < 4; ++nt)
        acc[mt][nt] = __builtin_amdgcn_mfma_f32_16x16x32_bf16(a, bfr[nt], acc[mt][nt], 0, 0, 0);
    }
  }
  #pragma unroll
  for (int mt = 0; mt < 8; ++mt){
    int hc0 = (wave*8+mt)*16 + quad*4;
    int h = hc0 >> 6, c0 = hc0 & 63;
    #pragma unroll
    for (int nt = 0; nt < 4; ++nt){
      int tok = t0 + nt*16 + l15;
      *(short4*)(vT + (size_t)h*2097152 + (size_t)tok*64 + c0)
        = pack4(acc[mt][nt][0], acc[mt][nt][1], acc[mt][nt][2], acc[mt][nt][3]);
    }
  }
}

// ======== k_phi1b: C^T. M=(c,m) 16384, N=i 128, K=j 128 ====================
// A = v gathers (8x u16, stride 32KB, L2), B = ky bf16 rows. Out: phi[h][i][c*256+m]
__global__ __launch_bounds__(256) void k_phi1b(const u16* __restrict__ kyb,
                                               const u16* __restrict__ vT,
                                               u16* __restrict__ phi, int b){
  int tid = threadIdx.x;
  int wave = tid>>6, lane = tid&63, quad = lane>>4, l15 = lane&15;
  int bid = blockIdx.x; int mblk = bid & 63, h = bid >> 6;
  int m0 = mblk*256;
  const u16* vTh = vT + (size_t)h*2097152;
  const u16* kyh = kyb + (size_t)(b*8+h)*16384;
  f32x4 acc[4][8];
  #pragma unroll
  for (int mt = 0; mt < 4; ++mt)
    #pragma unroll
    for (int nt = 0; nt < 8; ++nt) acc[mt][nt] = (f32x4){0.f,0.f,0.f,0.f};
  for (int ks = 0; ks < 4; ++ks){
    short8 bfr[8];
    #pragma unroll
    for (int nt = 0; nt < 8; ++nt)
      bfr[nt] = *(const short8*)(kyh + (size_t)(nt*16 + l15)*128 + ks*32 + quad*8);
    #pragma unroll
    for (int mt = 0; mt < 4; ++mt){
      int cm = m0 + (wave*4+mt)*16 + l15;
      int c = cm >> 8, m = cm & 255;
      const u16* gp = vTh + ((size_t)(ks*32 + quad*8)*256 + m)*64 + c;
      short8 a;
      #pragma unroll
      for (int jj = 0; jj < 8; ++jj) ((u16*)&a)[jj] = gp[(size_t)jj*16384];
      #pragma unroll
      for (int nt = 0; nt < 8; ++nt)
        acc[mt][nt] = __builtin_amdgcn_mfma_f32_16x16x32_bf16(a, bfr[nt], acc[mt][nt], 0, 0, 0);
    }
  }
  #pragma unroll
  for (int mt = 0; mt < 4; ++mt){
    int cmr = m0 + (wave*4+mt)*16 + quad*4;
    #pragma unroll
    for (int nt = 0; nt < 8; ++nt){
      int i = nt*16 + l15;
      *(short4*)(phi + (size_t)h*2097152 + (size_t)i*16384 + cmr)
        = pack4(acc[mt][nt][0], acc[mt][nt][1], acc[mt][nt][2], acc[mt][nt][3]);
    }
  }
}

// ======== k_phi2b: M=(i,c) 8192, N=l 256, K=m 256 ==========================
// A = phi rows (m-fastest), B = kx bf16 rows. Out: OUTt[h][l][i*64+c]
__global__ __launch_bounds__(256) void k_phi2b(const u16* __restrict__ kxb,
                                               const u16* __restrict__ phi,
                                               u16* __restrict__ OUTt, int b){
  int tid = threadIdx.x;
  int wave = tid>>6, lane = tid&63, quad = lane>>4, l15 = lane&15;
  int bid = blockIdx.x; int mblk = bid & 63, h = bid >> 6;
  int m0 = mblk*128;
  int mhalf = (wave&1)*4, nhalf = (wave>>1)*8;
  const u16* ph = phi + (size_t)h*2097152;
  const u16* kxh = kxb + (size_t)(b*8+h)*65536;
  f32x4 acc[4][8];
  #pragma unroll
  for (int mt = 0; mt < 4; ++mt)
    #pragma unroll
    for (int nt = 0; nt < 8; ++nt) acc[mt][nt] = (f32x4){0.f,0.f,0.f,0.f};
  for (int ks = 0; ks < 8; ++ks){
    short8 bfr[8];
    #pragma unroll
    for (int nt = 0; nt < 8; ++nt)
      bfr[nt] = *(const short8*)(kxh + (size_t)((nhalf+nt)*16 + l15)*256 + ks*32 + quad*8);
    #pragma unroll
    for (int mt = 0; mt < 4; ++mt){
      int m2 = m0 + (mhalf+mt)*16 + l15;
      short8 a = *(const short8*)(ph + (size_t)m2*256 + ks*32 + quad*8);
      #pragma unroll
      for (int nt = 0; nt < 8; ++nt)
        acc[mt][nt] = __builtin_amdgcn_mfma_f32_16x16x32_bf16(a, bfr[nt], acc[mt][nt], 0, 0, 0);
    }
  }
  #pragma unroll
  for (int mt = 0; mt < 4; ++mt){
    int m2r = m0 + (mhalf+mt)*16 + quad*4;
    #pragma unroll
    for (int nt = 0; nt < 8; ++nt){
      int l = (nhalf+nt)*16 + l15;
      *(short4*)(OUTt + (size_t)h*2097152 + (size_t)l*8192 + m2r)
        = pack4(acc[mt][nt][0], acc[mt][nt][1], acc[mt][nt][2], acc[mt][nt][3]);
    }
  }
}

// ======== k_gnb: GroupNorm over 64-c groups, coalesced ======================
// OUTt[h][l][i*64+c] -> gn[(i*256+l)][h*64+c]
__global__ __launch_bounds__(256) void k_gnb(const u16* __restrict__ OUTt,
                                             u16* __restrict__ gn){
  int tid = threadIdx.x;
  int bid = blockIdx.x; int l = bid & 255, h = bid >> 8;
  int i = tid >> 1, half = tid & 1;
  const u16* src = OUTt + (size_t)h*2097152 + (size_t)l*8192 + i*64 + half*32;
  float v[32]; float s1 = 0.f, s2 = 0.f;
  #pragma unroll
  for (int c4 = 0; c4 < 8; ++c4){
    short4 v4 = *(const short4*)(src + c4*4);
    v[c4*4+0] = bits2f((u16)v4.x); v[c4*4+1] = bits2f((u16)v4.y);
    v[c4*4+2] = bits2f((u16)v4.z); v[c4*4+3] = bits2f((u16)v4.w);
  }
  #pragma unroll
  for (int c = 0; c < 32; ++c){ s1 += v[c]; s2 += v[c]*v[c]; }
  s1 += __shfl_xor(s1, 1); s2 += __shfl_xor(s2, 1);
  float mean = s1*(1.0f/64.0f);
  float var = s2*(1.0f/64.0f) - mean*mean;
  float rstd = rsqrtf(var + 1e-6f);
  u16* dst = gn + ((size_t)(i*256 + l))*512 + h*64 + half*32;
  #pragma unroll
  for (int c4 = 0; c4 < 8; ++c4)
    *(short4*)(dst + c4*4) = pack4((v[c4*4+0]-mean)*rstd, (v[c4*4+1]-mean)*rstd,
                                   (v[c4*4+2]-mean)*rstd, (v[c4*4+3]-mean)*rstd);
}

// ======== k_mergeb: C^T. M=d 256, N=128 tokens, K=512 ======================
__global__ __launch_bounds__(256) void k_mergeb(const u16* __restrict__ gn,
                                                const u16* __restrict__ WmT,
                                                const float* __restrict__ biasm,
                                                const float* __restrict__ mod,
                                                const void* __restrict__ u,
                                                void* __restrict__ outv,
                                                const int* __restrict__ flag, int b){
  __shared__ float smg[256], sbb[256];
  int f = *flag;
  int tid = threadIdx.x;
  smg[tid] = mod[b*1536 + 512 + tid];
  sbb[tid] = biasm[tid];
  __syncthreads();
  int wave = tid>>6, lane = tid&63, quad = lane>>4, l15 = lane&15;
  int t0 = blockIdx.x*128;
  int nt0 = wave*2;
  f32x4 acc[16][2];
  #pragma unroll
  for (int mt = 0; mt < 16; ++mt){ acc[mt][0] = (f32x4){0.f,0.f,0.f,0.f}; acc[mt][1] = (f32x4){0.f,0.f,0.f,0.f}; }
  for (int ks = 0; ks < 16; ++ks){
    short8 bfr[2];
    #pragma unroll
    for (int nti = 0; nti < 2; ++nti){
      int tok = t0 + (nt0+nti)*16 + l15;
      bfr[nti] = *(const short8*)(gn + (size_t)tok*512 + ks*32 + quad*8);
    }
    #pragma unroll
    for (int mt = 0; mt < 16; ++mt){
      short8 a = *(const short8*)(WmT + (size_t)(mt*16 + l15)*512 + ks*32 + quad*8);
      #pragma unroll
      for (int nti = 0; nti < 2; ++nti)
        acc[mt][nti] = __builtin_amdgcn_mfma_f32_16x16x32_bf16(a, bfr[nti], acc[mt][nti], 0, 0, 0);
    }
  }
  #pragma unroll
  for (int mt = 0; mt < 16; ++mt){
    int d0 = mt*16 + quad*4;
    #pragma unroll
    for (int nti = 0; nti < 2; ++nti){
      int tok = t0 + (nt0+nti)*16 + l15;
      size_t o = ((size_t)b*32768 + tok)*256 + d0;
      float r0,r1,r2,r3;
      if (f){
        short4 rv = *(const short4*)((const bf16*)u + o);
        r0 = bits2f((u16)rv.x); r1 = bits2f((u16)rv.y); r2 = bits2f((u16)rv.z); r3 = bits2f((u16)rv.w);
      } else {
        float4 rv = *(const float4*)((const float*)u + o);
        r0 = rv.x; r1 = rv.y; r2 = rv.z; r3 = rv.w;
      }
      float y0 = r0 + smg[d0+0]*(acc[mt][nti][0] + sbb[d0+0]);
      float y1 = r1 + smg[d0+1]*(acc[mt][nti][1] + sbb[d0+1]);
      float y2 = r2 + smg[d0+2]*(acc[mt][nti][2] + sbb[d0+2]);
      float y3 = r3 + smg[d0+3]*(acc[mt][nti][3] + sbb[d0+3]);
      if (f) *(short4*)((bf16*)outv + o) = pack4(y0,y1,y2,y3);
      else   *(float4*)((float*)outv + o) = (float4){y0,y1,y2,y3};
    }
  }
}

// ======== k_ffn4: LDS-staged weights, 2-phase pipeline, per-wave LN ========
// 32 chunks of 32 hidden. Per chunk: 16KB w1 (contig at c*16384B) + 16KB w2
// (contig via k_wprep2 layout) staged into wbuf[2] by global_load_lds (16B),
// shared by all 4 waves. STAGE(c+1) -> compute(c) -> __syncthreads().
__global__ __launch_bounds__(256, 2) void k_ffn4(
    const float* __restrict__ mod,
    const u16* __restrict__ w1f,
    const float* __restrict__ b1c,
    const u16* __restrict__ w2f,
    const float* __restrict__ b2c,
    void* __restrict__ outv,
    const int* __restrict__ flag){
  __shared__ __align__(16) u16 wbuf[2][16384];   // 2 x 32KB
  __shared__ __align__(16) u16 hs[64][40];       // per-wave 16 rows x 32 (+8 pad)
  int f = *flag;
  int tid = threadIdx.x;
  int wave = tid>>6, lane = tid&63, quad = lane>>4, l15 = lane&15;
  int mrow = wave*16;
  int t0 = blockIdx.x*64;
  int bb = t0 >> 15;
  const float* modp = mod + bb*1536;
  size_t rowbase = ((size_t)(t0 + mrow + l15))*256;

  // ---- stage chunk 0 into wbuf[0] (async; overlaps the LN below) ----
  {
    #pragma unroll
    for (int i = 0; i < 8; ++i){
      int seg = wave*8 + i;
      const u16* src = (seg < 16)
          ? (w1f + (size_t)seg*512 + lane*8)
          : (w2f + (size_t)(seg-16)*512 + lane*8);
      stage16(src, &wbuf[0][seg*512]);
    }
  }

  // ---- LN in registers: load A-frags, row stats via cross-quad shuffles ----
  short8 afr[8];
  float s1 = 0.f, s2 = 0.f;
  #pragma unroll
  for (int ks = 0; ks < 8; ++ks){
    int c0 = ks*32 + quad*8;
    float v0,v1,v2,v3,v4,v5,v6,v7;
    if (f){
      short8 r = *(const short8*)((const bf16*)outv + rowbase + c0);
      afr[ks] = r;
      v0 = bits2f((u16)r[0]); v1 = bits2f((u16)r[1]); v2 = bits2f((u16)r[2]); v3 = bits2f((u16)r[3]);
      v4 = bits2f((u16)r[4]); v5 = bits2f((u16)r[5]); v6 = bits2f((u16)r[6]); v7 = bits2f((u16)r[7]);
    } else {
      float4 fa = *(const float4*)((const float*)outv + rowbase + c0);
      float4 fb = *(const float4*)((const float*)outv + rowbase + c0 + 4);
      v0=fa.x; v1=fa.y; v2=fa.z; v3=fa.w; v4=fb.x; v5=fb.y; v6=fb.z; v7=fb.w;
      afr[ks] = pack8(v0,v1,v2,v3,v4,v5,v6,v7);
    }
    s1 += v0+v1+v2+v3+v4+v5+v6+v7;
    s2 += v0*v0+v1*v1+v2*v2+v3*v3+v4*v4+v5*v5+v6*v6+v7*v7;
  }
  s1 += __shfl_xor(s1, 16); s1 += __shfl_xor(s1, 32);
  s2 += __shfl_xor(s2, 16); s2 += __shfl_xor(s2, 32);
  float mean = s1*(1.0f/256.0f);
  float var = s2*(1.0f/256.0f) - mean*mean;
  float rstd = rsqrtf(var + 1e-5f);
  #pragma unroll
  for (int ks = 0; ks < 8; ++ks){
    int c0 = ks*32 + quad*8;
    float4 sh0 = *(const float4*)&modp[768 + c0];
    float4 sh1 = *(const float4*)&modp[768 + c0 + 4];
    float4 sc0 = *(const float4*)&modp[1024 + c0];
    float4 sc1 = *(const float4*)&modp[1024 + c0 + 4];
    short8 r = afr[ks];
    float y0 = (bits2f((u16)r[0]) - mean)*rstd*(1.0f+sc0.x) + sh0.x;
    float y1 = (bits2f((u16)r[1]) - mean)*rstd*(1.0f+sc0.y) + sh0.y;
    float y2 = (bits2f((u16)r[2]) - mean)*rstd*(1.0f+sc0.z) + sh0.z;
    float y3 = (bits2f((u16)r[3]) - mean)*rstd*(1.0f+sc0.w) + sh0.w;
    float y4 = (bits2f((u16)r[4]) - mean)*rstd*(1.0f+sc1.x) + sh1.x;
    float y5 = (bits2f((u16)r[5]) - mean)*rstd*(1.0f+sc1.y) + sh1.y;
    float y6 = (bits2f((u16)r[6]) - mean)*rstd*(1.0f+sc1.z) + sh1.z;
    float y7 = (bits2f((u16)r[7]) - mean)*rstd*(1.0f+sc1.w) + sh1.w;
    afr[ks] = pack8(y0,y1,y2,y3,y4,y5,y6,y7);
  }

  __syncthreads();   // chunk 0 staged + all waves ready

  // ---- main loop: 32 chunks of 32 hidden, double-buffered weights ----
  f32x4 acc2[16];
  #pragma unroll
  for (int nt = 0; nt < 16; ++nt) acc2[nt] = (f32x4){0.f,0.f,0.f,0.f};
  int buf = 0;
  #pragma unroll 1
  for (int c = 0; c < 32; ++c){
    // prefetch chunk c+1 into the other buffer (async, drains at syncthreads)
    if (c < 31){
      int cn = c + 1;
      #pragma unroll
      for (int i = 0; i < 8; ++i){
        int seg = wave*8 + i;
        const u16* src = (seg < 16)
            ? (w1f + (size_t)cn*8192 + (size_t)seg*512 + lane*8)
            : (w2f + (size_t)cn*8192 + (size_t)(seg-16)*512 + lane*8);
        stage16(src, &wbuf[buf^1][seg*512]);
      }
    }
    const u16* w1l = &wbuf[buf][0];
    const u16* w2l = &wbuf[buf][8192];
    // gemm1: 16 tok x 32 hid, K=256 (B-frags from LDS, linear conflict-free)
    f32x4 acc1[2];
    acc1[0] = (f32x4){0.f,0.f,0.f,0.f}; acc1[1] = (f32x4){0.f,0.f,0.f,0.f};
    #pragma unroll
    for (int ks = 0; ks < 8; ++ks){
      #pragma unroll
      for (int nt2 = 0; nt2 < 2; ++nt2){
        short8 bfr = *(const short8*)(w1l + (nt2*8 + ks)*512 + lane*8);
        acc1[nt2] = __builtin_amdgcn_mfma_f32_16x16x32_bf16(afr[ks], bfr, acc1[nt2], 0, 0, 0);
      }
    }
    __builtin_amdgcn_sched_barrier(0);
    // gelu + transposed scalar writes to this wave's private hs rows
    #pragma unroll
    for (int nt2 = 0; nt2 < 2; ++nt2){
      int hid = nt2*16 + l15;
      float b1 = b1c[c*32 + hid];
      #pragma unroll
      for (int r = 0; r < 4; ++r)
        hs[mrow + quad*4 + r][hid] = f2bits(gelu_fast(acc1[nt2][r] + b1));
    }
    __builtin_amdgcn_sched_barrier(0);
    asm volatile("s_waitcnt lgkmcnt(0)" ::: "memory");
    __builtin_amdgcn_sched_barrier(0);
    // gemm2: 16 tok x 256 out, K=32 for this chunk
    short8 a2 = *(const short8*)&hs[mrow + l15][quad*8];
    #pragma unroll
    for (int nt = 0; nt < 16; ++nt){
      short8 bfr = *(const short8*)(w2l + nt*512 + lane*8);
      acc2[nt] = __builtin_amdgcn_mfma_f32_16x16x32_bf16(a2, bfr, acc2[nt], 0, 0, 0);
    }
    __syncthreads();   // drains prefetch vmcnt + hs reads done before overwrite
    buf ^= 1;
  }

  // ---- epilogue: direct register stores, u2 = u1 + g*(y + b2), in place ----
  #pragma unroll
  for (int nt = 0; nt < 16; ++nt){
    int col = nt*16 + l15;
    float g = modp[1280 + col];
    float b2v = b2c[col];
    #pragma unroll
    for (int r = 0; r < 4; ++r){
      size_t o = ((size_t)(t0 + mrow + quad*4 + r))*256 + col;
      float resid = f ? bits2f(((const u16*)outv)[o]) : ((const float*)outv)[o];
      float y = resid + g*(acc2[nt][r] + b2v);
      if (f) ((u16*)outv)[o] = f2bits(y);
      else   ((float*)outv)[o] = y;
    }
  }
}

extern "C" void kernel_launch(void* const* d_in, const int* in_sizes, int n_in,
                              void* d_out, int out_size, void* d_ws, size_t ws_size,
                              hipStream_t stream){
  (void)n_in; (void)out_size; (void)ws_size;

  char* p = (char*)d_ws;
  auto alloc = [&](size_t bytes)->void*{
    void* r = (void*)p; p += (bytes + 255) & ~(size_t)255; return r;
  };

  int* flag = (int*)alloc(4);
  float* cin[28];
  cin[0] = nullptr;
  for (int i = 1; i < 28; ++i) cin[i] = (float*)alloc((size_t)in_sizes[i]*4);

  float* mod  = (float*)alloc((size_t)4*1536*4);
  float* lw   = (float*)alloc((size_t)128*4);
  float* redx = (float*)alloc((size_t)4*256*256*4);
  float* redy = (float*)alloc((size_t)4*128*256*4);
  float* tx   = (float*)alloc((size_t)4*256*256*4);
  float* hx   = (float*)alloc((size_t)4*256*256*4);
  float* uxb  = (float*)alloc((size_t)4*256*128*4);
  float* ty   = (float*)alloc((size_t)4*128*256*4);
  float* hy   = (float*)alloc((size_t)4*128*256*4);
  float* uyb  = (float*)alloc((size_t)4*128*128*4);
  float* qkx  = (float*)alloc((size_t)4*256*1024*4);
  float* qky  = (float*)alloc((size_t)4*128*1024*4);
  float* radx = (float*)alloc((size_t)8*256*256*4);
  float* rady = (float*)alloc((size_t)8*128*128*4);
  u16* kxb = (u16*)alloc((size_t)32*256*256*2);
  u16* kyb = (u16*)alloc((size_t)32*128*128*2);
  u16* w1f = (u16*)alloc((size_t)256*1024*2);
  u16* w2f = (u16*)alloc((size_t)1024*256*2);
  u16* WvT = (u16*)alloc((size_t)512*256*2);
  u16* WmT = (u16*)alloc((size_t)256*512*2);
  u16* um    = (u16*)alloc((size_t)NTOK*256*2);        // 67 MB
  u16* slotV = (u16*)alloc((size_t)8*2097152*2);       // 33.5 MB
  u16* slotP = (u16*)alloc((size_t)8*2097152*2);       // 33.5 MB

  const void* u = d_in[0];

  k_detect<<<1, 1, 0, stream>>>(d_in[3], flag);
  for (int i = 1; i < 28; ++i){
    int n = in_sizes[i];
    int blocks = (n + 255)/256; if (blocks > 1024) blocks = 1024;
    k_cvt<<<blocks, 256, 0, stream>>>(d_in[i], cin[i], n, flag);
  }
  k_wprep<<<1024, 256, 0, stream>>>(cin[24], w1f, 8, 1024, 256*1024);
  k_wprep2<<<1024, 256, 0, stream>>>(cin[26], w2f);
  k_wtrans<<<512, 256, 0, stream>>>(cin[7],  WvT, 256, 512);   // to_v_w
  k_wtrans<<<512, 256, 0, stream>>>(cin[22], WmT, 512, 256);   // merge_w

  k_mod<<<24, 256, 0, stream>>>(cin[4], cin[5], cin[6], mod);
  k_lw<<<1, 128, 0, stream>>>(cin[1], lw);
  k_um2<<<NTOK/64, 256, 0, stream>>>(u, mod, um, flag);
  k_redx<<<1024, 256, 0, stream>>>(um, lw, redx);
  k_redy<<<512, 256, 0, stream>>>(um, redy);
  gemm_row<<<1024, 256, 0, stream>>>(redx, cin[8],  nullptr, tx,  256, 256, 0);
  gemm_row<<<1024, 256, 0, stream>>>(tx,   cin[9],  cin[10], hx,  256, 256, 1);
  gemm_row<<<1024, 256, 0, stream>>>(hx,   cin[11], cin[12], uxb, 256, 128, 0);
  gemm_row<<<1024, 256, 0, stream>>>(uxb,  cin[18], nullptr, qkx, 128, 1024, 0);
  gemm_row<<<512, 256, 0, stream>>>(redy, cin[13], nullptr, ty,  256, 256, 0);
  gemm_row<<<512, 256, 0, stream>>>(ty,   cin[14], cin[15], hy,  256, 256, 1);
  gemm_row<<<512, 256, 0, stream>>>(hy,   cin[16], cin[17], uyb, 256, 128, 0);
  gemm_row<<<512, 256, 0, stream>>>(uyb,  cin[19], nullptr, qky, 128, 1024, 0);
  k_radial<<<(8*256*256)/256, 256, 0, stream>>>(cin[3], cin[20], radx, 256);
  k_radial<<<(8*128*128)/256, 256, 0, stream>>>(cin[2], cin[21], rady, 128);
  k_attn<<<4*8*256, 256, (64+256)*4, stream>>>(qkx, radx, kxb, 256);
  k_attn<<<4*8*128, 128, (64+128)*4, stream>>>(qky, rady, kyb, 128);

  for (int b = 0; b < 4; ++b){
    u16* vTb  = slotV;   // vT[h][tok][c]
    u16* phb  = slotP;   // phi[h][i][c*256+m]
    u16* outt = slotV;   // OUTt[h][l][i*64+c]  (vT dead)
    u16* gnb  = slotP;   // gn[tok][h*64+c]     (phi dead)
    k_v2    <<<512, 256, 0, stream>>>(um, WvT, vTb, b);
    k_phi1b <<<512, 256, 0, stream>>>(kyb, vTb, phb, b);
    k_phi2b <<<512, 256, 0, stream>>>(kxb, phb, outt, b);
    k_gnb   <<<2048, 256, 0, stream>>>(outt, gnb);
    k_mergeb<<<256, 256, 0, stream>>>(gnb, WmT, cin[23], mod, u, d_out, flag, b);
  }
  k_ffn4<<<NTOK/64, 256, 0, stream>>>(mod, w1f, cin[25], w2f, cin[27], d_out, flag);
}

// Round 3
// 1796.488 us; speedup vs baseline: 1.6643x; 1.1044x over previous
//
#include <hip/hip_runtime.h>
#include <hip/hip_bf16.h>
#include <math.h>

// FADiTBlockS2: b=4, nlat=128, nlon=256, dim=256, H=8, DH=64, BNECK=128, NK=32
// Round 7: k_ffn4 validated (1338->353us, MfmaUtil 16%). Now the MSA chain:
//  - b-loop merged into grid (20 -> 5 launches, 4x TLP); slot buffers get a
//    per-b stride; runtime ws_size check falls back to per-b loop (stride 0)
//  - k_attn2: K pre-transposed to [(b,h,d)][j] for coalesced j-reads,
//    wave-shuffle reductions (2 barriers instead of 16)
//  - gemm_row2: x+y bottleneck chains fused per stage (8 -> 4 launches),
//    4-way accumulator unroll breaks the serial FMA chain

#define B_ 4
#define NLAT 128
#define NLON 256
#define NTOK (B_*NLAT*NLON)   // 131072
#define SLOT_ELE ((size_t)16777216)   // per-b slot elements (8h x 32768tok x 64c)

typedef __hip_bfloat16 bf16;
typedef unsigned short u16;
typedef __attribute__((ext_vector_type(8))) short short8;
typedef __attribute__((ext_vector_type(4))) float f32x4;

__device__ __forceinline__ float b2f(bf16 x){ return __bfloat162float(x); }
__device__ __forceinline__ bf16  f2b(float x){ return __float2bfloat16(x); }
__device__ __forceinline__ u16 f2bits(float x){
  bf16 h = __float2bfloat16(x); return *(u16*)&h;
}
__device__ __forceinline__ float bits2f(u16 u){
  union { unsigned int i; float f; } v; v.i = ((unsigned int)u) << 16; return v.f;
}
__device__ __forceinline__ float gelu_f(float x){
  float x3 = x*x*x;
  return 0.5f*x*(1.0f + tanhf(0.7978845608028654f*(x + 0.044715f*x3)));
}
// identity-exact fast gelu: tanh(t) = 1 - 2/(exp2(t*2/ln2)+1)
__device__ __forceinline__ float gelu_fast(float x){
  float t = 0.7978845608028654f*(x + 0.044715f*x*x*x);
  float e = __builtin_amdgcn_exp2f(t * 2.8853900817779268f);
  return x - x*__builtin_amdgcn_rcpf(e + 1.0f);
}
__device__ __forceinline__ float ldin(const void* p, size_t i, int flag){
  return flag ? b2f(((const bf16*)p)[i]) : ((const float*)p)[i];
}
__device__ __forceinline__ short4 pack4(float a, float b, float c, float d){
  short4 r; r.x = (short)f2bits(a); r.y = (short)f2bits(b);
  r.z = (short)f2bits(c); r.w = (short)f2bits(d); return r;
}
__device__ __forceinline__ short8 pack8(float a, float b, float c, float d,
                                        float e, float f, float g, float h){
  short8 r;
  r[0]=(short)f2bits(a); r[1]=(short)f2bits(b); r[2]=(short)f2bits(c); r[3]=(short)f2bits(d);
  r[4]=(short)f2bits(e); r[5]=(short)f2bits(f); r[6]=(short)f2bits(g); r[7]=(short)f2bits(h);
  return r;
}
// async global->LDS 16B: lds dest is wave-uniform base (+lane*16 by HW),
// global src is per-lane.
__device__ __forceinline__ void stage16(const u16* g, u16* l){
  __builtin_amdgcn_global_load_lds(
      (const __attribute__((address_space(1))) void*)g,
      (__attribute__((address_space(3))) void*)l, 16, 0, 0);
}

// ---------------- dtype detection: lon_diff[1] == 2*pi/256 -----------------
__global__ void k_detect(const void* lon_diff, int* flag){
  const float c = 0.02454369260617026f;
  float asF = ((const float*)lon_diff)[1];
  float asB = b2f(((const bf16*)lon_diff)[1]);
  float ef = fabsf(asF - c), eb = fabsf(asB - c);
  if (!isfinite(ef)) ef = 1e30f;
  *flag = (eb < ef) ? 1 : 0;   // 1 = bf16 buffers, 0 = f32 buffers
}

__global__ __launch_bounds__(256) void k_cvt(const void* __restrict__ src,
                                             float* __restrict__ dst, int n,
                                             const int* __restrict__ flag){
  int f = *flag;
  for (int i = blockIdx.x*256 + threadIdx.x; i < n; i += gridDim.x*256)
    dst[i] = ldin(src, i, f);
}

// ------- pack weight [K][N] f32 -> fragment-order bf16 ([nt][ks][lane][8]) -
__global__ __launch_bounds__(256) void k_wprep(const float* __restrict__ W,
                                               u16* __restrict__ wf,
                                               int KS, int ldn, int total){
  int gid = blockIdx.x*256 + threadIdx.x;
  if (gid >= total) return;
  int j = gid & 7; int lane = (gid >> 3) & 63; int rest = gid >> 9;
  int ks = rest % KS; int nt = rest / KS;
  int k = ks*32 + (lane >> 4)*8 + j;
  int n = nt*16 + (lane & 15);
  wf[gid] = f2bits(W[(size_t)k*ldn + n]);
}

// ------- w2 pack: [ksAll 0..31][nt 0..15][lane][8]; W2 is [1024][256] ------
__global__ __launch_bounds__(256) void k_wprep2(const float* __restrict__ W,
                                                u16* __restrict__ wf){
  int gid = blockIdx.x*256 + threadIdx.x;   // 262144 total
  int j = gid & 7; int lane = (gid >> 3) & 63; int rest = gid >> 9;
  int nt = rest & 15; int ksAll = rest >> 4;
  int k = ksAll*32 + (lane >> 4)*8 + j;
  int n = nt*16 + (lane & 15);
  wf[gid] = f2bits(W[(size_t)k*256 + n]);
}

// ------- transposed bf16 copy: WT[n][k] = W[k][n] ---------------------------
__global__ __launch_bounds__(256) void k_wtrans(const float* __restrict__ W,
                                                u16* __restrict__ WT, int K, int N){
  int gid = blockIdx.x*256 + threadIdx.x;
  if (gid >= K*N) return;
  int k = gid % K, n = gid / K;
  WT[(size_t)n*K + k] = f2bits(W[(size_t)k*N + n]);
}

// ---------------- mod = scalar_cond @ adaLN_w + adaLN_b  (4 x 1536) --------
__global__ __launch_bounds__(256) void k_mod(const float* __restrict__ sc,
                                             const float* __restrict__ w,
                                             const float* __restrict__ bias,
                                             float* __restrict__ mod){
  int gid = blockIdx.x*256 + threadIdx.x;
  int s = gid / 1536, j = gid % 1536;
  float acc = bias[j];
  for (int c = 0; c < 256; ++c) acc += sc[s*256+c] * w[c*1536+j];
  mod[gid] = acc;
}

// ---------------- lw = cos(lat)/mean(cos(lat)) -----------------------------
__global__ __launch_bounds__(128) void k_lw(const float* __restrict__ lat,
                                            float* __restrict__ lw){
  __shared__ float red[128];
  int i = threadIdx.x;
  float cv = cosf(lat[i]);
  red[i] = cv; __syncthreads();
  for (int s = 64; s > 0; s >>= 1){ if (i < s) red[i] += red[i+s]; __syncthreads(); }
  float mean = red[0] * (1.0f/128.0f);
  lw[i] = cv / mean;
}

// ------- um = LN(u)*(1+sc_msa)+sh_msa : 64 tokens/block, coalesced ---------
__global__ __launch_bounds__(256) void k_um2(const void* __restrict__ u,
                                             const float* __restrict__ mod,
                                             u16* __restrict__ um,
                                             const int* __restrict__ flag){
  __shared__ u16 tile[64][264];
  __shared__ float r1[64][4], r2[64][4], mv[64], rs[64];
  __shared__ float ssh[256], ssc[256];
  int f = *flag; int tid = threadIdx.x;
  int t0 = blockIdx.x*64; int b = t0 >> 15;
  ssh[tid] = mod[b*1536 + tid];
  ssc[tid] = mod[b*1536 + 256 + tid];
  // phase 1: coalesced load -> bf16 tile
  for (int it = 0; it < 16; ++it){
    int idx = it*256 + tid;       // 4096 vec4 groups
    int tok = idx >> 6, c4 = idx & 63;
    short4 v4;
    if (f){
      v4 = *(const short4*)((const bf16*)u + ((size_t)(t0+tok))*256 + c4*4);
    } else {
      float4 fv = ((const float4*)u)[((size_t)(t0+tok))*64 + c4];
      v4 = pack4(fv.x, fv.y, fv.z, fv.w);
    }
    *(short4*)&tile[tok][c4*4] = v4;
  }
  __syncthreads();
  // phase 2: stats (4 threads per token)
  {
    int tok = tid >> 2, part = tid & 3;
    float s1 = 0.f, s2 = 0.f;
    for (int c4 = 0; c4 < 16; ++c4){
      short4 v4 = *(const short4*)&tile[tok][part*64 + c4*4];
      float a = bits2f((u16)v4.x), bb = bits2f((u16)v4.y),
            c = bits2f((u16)v4.z), d = bits2f((u16)v4.w);
      s1 += a+bb+c+d; s2 += a*a+bb*bb+c*c+d*d;
    }
    r1[tok][part] = s1; r2[tok][part] = s2;
  }
  __syncthreads();
  if ((tid & 3) == 0){
    int tok = tid >> 2;
    float a1 = r1[tok][0]+r1[tok][1]+r1[tok][2]+r1[tok][3];
    float a2 = r2[tok][0]+r2[tok][1]+r2[tok][2]+r2[tok][3];
    float mean = a1*(1.0f/256.0f);
    float var = a2*(1.0f/256.0f) - mean*mean;
    mv[tok] = mean; rs[tok] = rsqrtf(var + 1e-5f);
  }
  __syncthreads();
  // phase 3: modulate + coalesced store
  for (int it = 0; it < 16; ++it){
    int idx = it*256 + tid;
    int tok = idx >> 6, c4 = idx & 63;
    float mean = mv[tok], rstd = rs[tok];
    short4 v4 = *(const short4*)&tile[tok][c4*4];
    float y[4]; u16 raw[4] = {(u16)v4.x,(u16)v4.y,(u16)v4.z,(u16)v4.w};
    #pragma unroll
    for (int p = 0; p < 4; ++p){
      int c = c4*4 + p;
      y[p] = (bits2f(raw[p]) - mean)*rstd*(1.0f + ssc[c]) + ssh[c];
    }
    *(short4*)(um + ((size_t)(t0+tok))*256 + c4*4) = pack4(y[0],y[1],y[2],y[3]);
  }
}

// ---------------- redx[b,l,c] = (1/128) * sum_i um[b,i,l,c]*lw[i] ----------
__global__ __launch_bounds__(256) void k_redx(const u16* __restrict__ um,
                                              const float* __restrict__ lw,
                                              float* __restrict__ redx){
  __shared__ float lws[128];
  int tid = threadIdx.x;
  if (tid < 128) lws[tid] = lw[tid];
  __syncthreads();
  int gid = blockIdx.x*256 + tid;
  int c = gid & 255; int l = (gid >> 8) & 255; int b = gid >> 16;
  float acc = 0.0f;
  for (int i = 0; i < 128; ++i)
    acc += bits2f(um[(((size_t)(b*128 + i)*256 + l)*256) + c]) * lws[i];
  redx[gid] = acc * (1.0f/128.0f);
}

__global__ __launch_bounds__(256) void k_redy(const u16* __restrict__ um,
                                              float* __restrict__ redy){
  int gid = blockIdx.x*256 + threadIdx.x;
  int c = gid & 255; int i = (gid >> 8) & 127; int b = gid >> 15;
  float acc = 0.0f;
  for (int l = 0; l < 256; ++l)
    acc += bits2f(um[(((size_t)(b*128 + i)*256 + l)*256) + c]);
  redy[gid] = acc * (1.0f/256.0f);
}

// ------- dual row GEMM: x-chain rows [0,nbx), y-chain rows [nbx,nbx+nby) ---
__global__ __launch_bounds__(256) void gemm_row2(
    const float* __restrict__ Ax, const float* __restrict__ Wx,
    const float* __restrict__ bx, float* __restrict__ Cx, int Kx, int Nx,
    const float* __restrict__ Ay, const float* __restrict__ Wy,
    const float* __restrict__ by, float* __restrict__ Cy, int Ky, int Ny,
    int nbx, int act){
  __shared__ float As[256];
  int bid = blockIdx.x; int tid = threadIdx.x;
  const float* A; const float* W; const float* bias; float* C; int K, N, r;
  if (bid < nbx){ A=Ax; W=Wx; bias=bx; C=Cx; K=Kx; N=Nx; r=bid; }
  else          { A=Ay; W=Wy; bias=by; C=Cy; K=Ky; N=Ny; r=bid-nbx; }
  for (int k = tid; k < K; k += 256) As[k] = A[(size_t)r*K + k];
  __syncthreads();
  for (int n = tid; n < N; n += 256){
    float a0=0.f, a1=0.f, a2=0.f, a3=0.f;
    for (int k = 0; k < K; k += 4){
      a0 += As[k+0]*W[(size_t)(k+0)*N + n];
      a1 += As[k+1]*W[(size_t)(k+1)*N + n];
      a2 += As[k+2]*W[(size_t)(k+2)*N + n];
      a3 += As[k+3]*W[(size_t)(k+3)*N + n];
    }
    float acc = (a0+a1)+(a2+a3) + (bias ? bias[n] : 0.0f);
    if (act == 1) acc = gelu_f(acc);
    C[(size_t)r*N + n] = acc;
  }
}

// ---------------- radial[h,i,j] ---------------------------------------------
__global__ __launch_bounds__(256) void k_radial(const float* __restrict__ d,
                                                const float* __restrict__ w,
                                                float* __restrict__ rad, int n){
  int gid = blockIdx.x*256 + threadIdx.x;
  int nn = n*n;
  int h = gid / nn; int rem = gid % nn;
  float dv = d[rem];
  float safe = fmaxf(dv, 1e-6f);
  float acc = 0.0f;
  for (int k = 0; k < 32; ++k){
    float nk = (float)(k+1);
    float basis = (dv > 1e-6f) ? (sinf(dv*nk)/safe) : nk;
    acc += basis * w[k*8 + h];
  }
  rad[gid] = acc;
}

// ------- kT[((b*8+h)*64+d)][j] = qk[(b*n+j)][512+h*64+d]  (coalesced j) ----
__global__ __launch_bounds__(256) void k_qkT(const float* __restrict__ qk,
                                             float* __restrict__ kT, int n){
  int gid = blockIdx.x*256 + threadIdx.x;   // 4*8*64*n total
  int j = gid % n; int rest = gid / n;
  int d = rest & 63; int bh = rest >> 6;
  int b = bh >> 3, h = bh & 7;
  kT[gid] = qk[((size_t)(b*n + j))*1024 + 512 + h*64 + d];
}

// ------- attention weights -> bf16 rows [bh][i][j], coalesced K reads ------
__global__ __launch_bounds__(256) void k_attn2(const float* __restrict__ qk,
                                               const float* __restrict__ kT,
                                               const float* __restrict__ rad,
                                               u16* __restrict__ kout, int n){
  extern __shared__ float sm[];   // qs[64] + red[8]
  float* qs = sm; float* red = sm + 64;
  int j = threadIdx.x;
  int bid = blockIdx.x; int i = bid % n; int h = (bid / n) & 7; int b = bid / (n*8);
  if (j < 64) qs[j] = qk[((size_t)(b*n + i))*1024 + h*64 + j];
  __syncthreads();
  const float* kcol = kT + ((size_t)((b*8 + h)*64))*n + j;
  float dot = 0.0f;
  #pragma unroll 8
  for (int d0 = 0; d0 < 64; ++d0) dot += qs[d0]*kcol[(size_t)d0*n];
  float s = dot * rad[((size_t)(h*n + i))*n + j];
  // block max: wave shuffle + tiny LDS cross-wave
  float m = s;
  #pragma unroll
  for (int off = 32; off; off >>= 1) m = fmaxf(m, __shfl_xor(m, off));
  int wv = j >> 6, nw = n >> 6;
  if ((j & 63) == 0) red[wv] = m;
  __syncthreads();
  m = red[0];
  for (int w = 1; w < nw; ++w) m = fmaxf(m, red[w]);
  float e = __builtin_amdgcn_exp2f((s - m)*1.44269504088896f);
  float t = e;
  #pragma unroll
  for (int off = 32; off; off >>= 1) t += __shfl_xor(t, off);
  if ((j & 63) == 0) red[4 + wv] = t;
  __syncthreads();
  t = 0.0f;
  for (int w = 0; w < nw; ++w) t += red[4 + w];
  kout[(size_t)bid*n + j] = f2bits(e / t);
}

// ======== k_v2: v-proj, C^T form. M=512 hc, N=64 tokens, K=256 =============
// merged-b: grid nb*512, b = b0 + bid>>9; buffers strided by bstr elements.
__global__ __launch_bounds__(256) void k_v2(const u16* __restrict__ um,
                                            const u16* __restrict__ WvT,
                                            u16* __restrict__ vT,
                                            int b0, size_t bstr){
  int tid = threadIdx.x;
  int wave = tid>>6, lane = tid&63, quad = lane>>4, l15 = lane&15;
  int bid = blockIdx.x;
  int b = b0 + (bid >> 9);
  int t0 = (bid & 511)*64;
  u16* vTb = vT + (size_t)(b - b0)*bstr;
  const u16* umb = um + ((size_t)b*32768 + t0)*256;
  f32x4 acc[8][4];
  #pragma unroll
  for (int mt = 0; mt < 8; ++mt)
    #pragma unroll
    for (int nt = 0; nt < 4; ++nt) acc[mt][nt] = (f32x4){0.f,0.f,0.f,0.f};
  for (int ks = 0; ks < 8; ++ks){
    short8 bfr[4];
    #pragma unroll
    for (int nt = 0; nt < 4; ++nt)
      bfr[nt] = *(const short8*)(umb + (size_t)(nt*16 + l15)*256 + ks*32 + quad*8);
    #pragma unroll
    for (int mt = 0; mt < 8; ++mt){
      short8 a = *(const short8*)(WvT + (size_t)((wave*8+mt)*16 + l15)*256 + ks*32 + quad*8);
      #pragma unroll
      for (int nt = 0; nt < 4; ++nt)
        acc[mt][nt] = __builtin_amdgcn_mfma_f32_16x16x32_bf16(a, bfr[nt], acc[mt][nt], 0, 0, 0);
    }
  }
  #pragma unroll
  for (int mt = 0; mt < 8; ++mt){
    int hc0 = (wave*8+mt)*16 + quad*4;
    int h = hc0 >> 6, c0 = hc0 & 63;
    #pragma unroll
    for (int nt = 0; nt < 4; ++nt){
      int tok = t0 + nt*16 + l15;
      *(short4*)(vTb + (size_t)h*2097152 + (size_t)tok*64 + c0)
        = pack4(acc[mt][nt][0], acc[mt][nt][1], acc[mt][nt][2], acc[mt][nt][3]);
    }
  }
}

// ======== k_phi1b: C^T. M=(c,m) 16384, N=i 128, K=j 128 ====================
__global__ __launch_bounds__(256) void k_phi1b(const u16* __restrict__ kyb,
                                               const u16* __restrict__ vT,
                                               u16* __restrict__ phi,
                                               int b0, size_t bstr){
  int tid = threadIdx.x;
  int wave = tid>>6, lane = tid&63, quad = lane>>4, l15 = lane&15;
  int bid = blockIdx.x;
  int b = b0 + (bid >> 9);
  int rem = bid & 511; int mblk = rem & 63, h = rem >> 6;
  int m0 = mblk*256;
  const u16* vTh = vT + (size_t)(b - b0)*bstr + (size_t)h*2097152;
  u16* phib = phi + (size_t)(b - b0)*bstr;
  const u16* kyh = kyb + (size_t)(b*8+h)*16384;
  f32x4 acc[4][8];
  #pragma unroll
  for (int mt = 0; mt < 4; ++mt)
    #pragma unroll
    for (int nt = 0; nt < 8; ++nt) acc[mt][nt] = (f32x4){0.f,0.f,0.f,0.f};
  for (int ks = 0; ks < 4; ++ks){
    short8 bfr[8];
    #pragma unroll
    for (int nt = 0; nt < 8; ++nt)
      bfr[nt] = *(const short8*)(kyh + (size_t)(nt*16 + l15)*128 + ks*32 + quad*8);
    #pragma unroll
    for (int mt = 0; mt < 4; ++mt){
      int cm = m0 + (wave*4+mt)*16 + l15;
      int c = cm >> 8, m = cm & 255;
      const u16* gp = vTh + ((size_t)(ks*32 + quad*8)*256 + m)*64 + c;
      short8 a;
      #pragma unroll
      for (int jj = 0; jj < 8; ++jj) ((u16*)&a)[jj] = gp[(size_t)jj*16384];
      #pragma unroll
      for (int nt = 0; nt < 8; ++nt)
        acc[mt][nt] = __builtin_amdgcn_mfma_f32_16x16x32_bf16(a, bfr[nt], acc[mt][nt], 0, 0, 0);
    }
  }
  #pragma unroll
  for (int mt = 0; mt < 4; ++mt){
    int cmr = m0 + (wave*4+mt)*16 + quad*4;
    #pragma unroll
    for (int nt = 0; nt < 8; ++nt){
      int i = nt*16 + l15;
      *(short4*)(phib + (size_t)h*2097152 + (size_t)i*16384 + cmr)
        = pack4(acc[mt][nt][0], acc[mt][nt][1], acc[mt][nt][2], acc[mt][nt][3]);
    }
  }
}

// ======== k_phi2b: M=(i,c) 8192, N=l 256, K=m 256 ==========================
__global__ __launch_bounds__(256) void k_phi2b(const u16* __restrict__ kxb,
                                               const u16* __restrict__ phi,
                                               u16* __restrict__ OUTt,
                                               int b0, size_t bstr){
  int tid = threadIdx.x;
  int wave = tid>>6, lane = tid&63, quad = lane>>4, l15 = lane&15;
  int bid = blockIdx.x;
  int b = b0 + (bid >> 9);
  int rem = bid & 511; int mblk = rem & 63, h = rem >> 6;
  int m0 = mblk*128;
  int mhalf = (wave&1)*4, nhalf = (wave>>1)*8;
  const u16* ph = phi + (size_t)(b - b0)*bstr + (size_t)h*2097152;
  u16* OUTb = OUTt + (size_t)(b - b0)*bstr;
  const u16* kxh = kxb + (size_t)(b*8+h)*65536;
  f32x4 acc[4][8];
  #pragma unroll
  for (int mt = 0; mt < 4; ++mt)
    #pragma unroll
    for (int nt = 0; nt < 8; ++nt) acc[mt][nt] = (f32x4){0.f,0.f,0.f,0.f};
  for (int ks = 0; ks < 8; ++ks){
    short8 bfr[8];
    #pragma unroll
    for (int nt = 0; nt < 8; ++nt)
      bfr[nt] = *(const short8*)(kxh + (size_t)((nhalf+nt)*16 + l15)*256 + ks*32 + quad*8);
    #pragma unroll
    for (int mt = 0; mt < 4; ++mt){
      int m2 = m0 + (mhalf+mt)*16 + l15;
      short8 a = *(const short8*)(ph + (size_t)m2*256 + ks*32 + quad*8);
      #pragma unroll
      for (int nt = 0; nt < 8; ++nt)
        acc[mt][nt] = __builtin_amdgcn_mfma_f32_16x16x32_bf16(a, bfr[nt], acc[mt][nt], 0, 0, 0);
    }
  }
  #pragma unroll
  for (int mt = 0; mt < 4; ++mt){
    int m2r = m0 + (mhalf+mt)*16 + quad*4;
    #pragma unroll
    for (int nt = 0; nt < 8; ++nt){
      int l = (nhalf+nt)*16 + l15;
      *(short4*)(OUTb + (size_t)h*2097152 + (size_t)l*8192 + m2r)
        = pack4(acc[mt][nt][0], acc[mt][nt][1], acc[mt][nt][2], acc[mt][nt][3]);
    }
  }
}

// ======== k_gnb: GroupNorm over 64-c groups, coalesced ======================
__global__ __launch_bounds__(256) void k_gnb(const u16* __restrict__ OUTt,
                                             u16* __restrict__ gn,
                                             int b0, size_t bstr){
  int tid = threadIdx.x;
  int bid = blockIdx.x;
  int bi = bid >> 11;
  int rem = bid & 2047; int l = rem & 255, h = rem >> 8;
  int i = tid >> 1, half = tid & 1;
  const u16* src = OUTt + (size_t)bi*bstr + (size_t)h*2097152 + (size_t)l*8192 + i*64 + half*32;
  float v[32]; float s1 = 0.f, s2 = 0.f;
  #pragma unroll
  for (int c4 = 0; c4 < 8; ++c4){
    short4 v4 = *(const short4*)(src + c4*4);
    v[c4*4+0] = bits2f((u16)v4.x); v[c4*4+1] = bits2f((u16)v4.y);
    v[c4*4+2] = bits2f((u16)v4.z); v[c4*4+3] = bits2f((u16)v4.w);
  }
  #pragma unroll
  for (int c = 0; c < 32; ++c){ s1 += v[c]; s2 += v[c]*v[c]; }
  s1 += __shfl_xor(s1, 1); s2 += __shfl_xor(s2, 1);
  float mean = s1*(1.0f/64.0f);
  float var = s2*(1.0f/64.0f) - mean*mean;
  float rstd = rsqrtf(var + 1e-6f);
  u16* dst = gn + (size_t)bi*bstr + ((size_t)(i*256 + l))*512 + h*64 + half*32;
  #pragma unroll
  for (int c4 = 0; c4 < 8; ++c4)
    *(short4*)(dst + c4*4) = pack4((v[c4*4+0]-mean)*rstd, (v[c4*4+1]-mean)*rstd,
                                   (v[c4*4+2]-mean)*rstd, (v[c4*4+3]-mean)*rstd);
}

// ======== k_mergeb: C^T. M=d 256, N=128 tokens, K=512 ======================
__global__ __launch_bounds__(256) void k_mergeb(const u16* __restrict__ gn,
                                                const u16* __restrict__ WmT,
                                                const float* __restrict__ biasm,
                                                const float* __restrict__ mod,
                                                const void* __restrict__ u,
                                                void* __restrict__ outv,
                                                const int* __restrict__ flag,
                                                int b0, size_t bstr){
  __shared__ float smg[256], sbb[256];
  int f = *flag;
  int tid = threadIdx.x;
  int bid = blockIdx.x;
  int b = b0 + (bid >> 8);
  int t0 = (bid & 255)*128;
  smg[tid] = mod[b*1536 + 512 + tid];
  sbb[tid] = biasm[tid];
  __syncthreads();
  int wave = tid>>6, lane = tid&63, quad = lane>>4, l15 = lane&15;
  const u16* gnb = gn + (size_t)(b - b0)*bstr;
  int nt0 = wave*2;
  f32x4 acc[16][2];
  #pragma unroll
  for (int mt = 0; mt < 16; ++mt){ acc[mt][0] = (f32x4){0.f,0.f,0.f,0.f}; acc[mt][1] = (f32x4){0.f,0.f,0.f,0.f}; }
  for (int ks = 0; ks < 16; ++ks){
    short8 bfr[2];
    #pragma unroll
    for (int nti = 0; nti < 2; ++nti){
      int tok = t0 + (nt0+nti)*16 + l15;
      bfr[nti] = *(const short8*)(gnb + (size_t)tok*512 + ks*32 + quad*8);
    }
    #pragma unroll
    for (int mt = 0; mt < 16; ++mt){
      short8 a = *(const short8*)(WmT + (size_t)(mt*16 + l15)*512 + ks*32 + quad*8);
      #pragma unroll
      for (int nti = 0; nti < 2; ++nti)
        acc[mt][nti] = __builtin_amdgcn_mfma_f32_16x16x32_bf16(a, bfr[nti], acc[mt][nti], 0, 0, 0);
    }
  }
  #pragma unroll
  for (int mt = 0; mt < 16; ++mt){
    int d0 = mt*16 + quad*4;
    #pragma unroll
    for (int nti = 0; nti < 2; ++nti){
      int tok = t0 + (nt0+nti)*16 + l15;
      size_t o = ((size_t)b*32768 + tok)*256 + d0;
      float r0,r1,r2,r3;
      if (f){
        short4 rv = *(const short4*)((const bf16*)u + o);
        r0 = bits2f((u16)rv.x); r1 = bits2f((u16)rv.y); r2 = bits2f((u16)rv.z); r3 = bits2f((u16)rv.w);
      } else {
        float4 rv = *(const float4*)((const float*)u + o);
        r0 = rv.x; r1 = rv.y; r2 = rv.z; r3 = rv.w;
      }
      float y0 = r0 + smg[d0+0]*(acc[mt][nti][0] + sbb[d0+0]);
      float y1 = r1 + smg[d0+1]*(acc[mt][nti][1] + sbb[d0+1]);
      float y2 = r2 + smg[d0+2]*(acc[mt][nti][2] + sbb[d0+2]);
      float y3 = r3 + smg[d0+3]*(acc[mt][nti][3] + sbb[d0+3]);
      if (f) *(short4*)((bf16*)outv + o) = pack4(y0,y1,y2,y3);
      else   *(float4*)((float*)outv + o) = (float4){y0,y1,y2,y3};
    }
  }
}

// ======== k_ffn4: LDS-staged weights, 2-phase pipeline, per-wave LN ========
__global__ __launch_bounds__(256, 2) void k_ffn4(
    const float* __restrict__ mod,
    const u16* __restrict__ w1f,
    const float* __restrict__ b1c,
    const u16* __restrict__ w2f,
    const float* __restrict__ b2c,
    void* __restrict__ outv,
    const int* __restrict__ flag){
  __shared__ __align__(16) u16 wbuf[2][16384];   // 2 x 32KB
  __shared__ __align__(16) u16 hs[64][40];       // per-wave 16 rows x 32 (+8 pad)
  int f = *flag;
  int tid = threadIdx.x;
  int wave = tid>>6, lane = tid&63, quad = lane>>4, l15 = lane&15;
  int mrow = wave*16;
  int t0 = blockIdx.x*64;
  int bb = t0 >> 15;
  const float* modp = mod + bb*1536;
  size_t rowbase = ((size_t)(t0 + mrow + l15))*256;

  // ---- stage chunk 0 into wbuf[0] (async; overlaps the LN below) ----
  {
    #pragma unroll
    for (int i = 0; i < 8; ++i){
      int seg = wave*8 + i;
      const u16* src = (seg < 16)
          ? (w1f + (size_t)seg*512 + lane*8)
          : (w2f + (size_t)(seg-16)*512 + lane*8);
      stage16(src, &wbuf[0][seg*512]);
    }
  }

  // ---- LN in registers ----
  short8 afr[8];
  float s1 = 0.f, s2 = 0.f;
  #pragma unroll
  for (int ks = 0; ks < 8; ++ks){
    int c0 = ks*32 + quad*8;
    float v0,v1,v2,v3,v4,v5,v6,v7;
    if (f){
      short8 r = *(const short8*)((const bf16*)outv + rowbase + c0);
      afr[ks] = r;
      v0 = bits2f((u16)r[0]); v1 = bits2f((u16)r[1]); v2 = bits2f((u16)r[2]); v3 = bits2f((u16)r[3]);
      v4 = bits2f((u16)r[4]); v5 = bits2f((u16)r[5]); v6 = bits2f((u16)r[6]); v7 = bits2f((u16)r[7]);
    } else {
      float4 fa = *(const float4*)((const float*)outv + rowbase + c0);
      float4 fb = *(const float4*)((const float*)outv + rowbase + c0 + 4);
      v0=fa.x; v1=fa.y; v2=fa.z; v3=fa.w; v4=fb.x; v5=fb.y; v6=fb.z; v7=fb.w;
      afr[ks] = pack8(v0,v1,v2,v3,v4,v5,v6,v7);
    }
    s1 += v0+v1+v2+v3+v4+v5+v6+v7;
    s2 += v0*v0+v1*v1+v2*v2+v3*v3+v4*v4+v5*v5+v6*v6+v7*v7;
  }
  s1 += __shfl_xor(s1, 16); s1 += __shfl_xor(s1, 32);
  s2 += __shfl_xor(s2, 16); s2 += __shfl_xor(s2, 32);
  float mean = s1*(1.0f/256.0f);
  float var = s2*(1.0f/256.0f) - mean*mean;
  float rstd = rsqrtf(var + 1e-5f);
  #pragma unroll
  for (int ks = 0; ks < 8; ++ks){
    int c0 = ks*32 + quad*8;
    float4 sh0 = *(const float4*)&modp[768 + c0];
    float4 sh1 = *(const float4*)&modp[768 + c0 + 4];
    float4 sc0 = *(const float4*)&modp[1024 + c0];
    float4 sc1 = *(const float4*)&modp[1024 + c0 + 4];
    short8 r = afr[ks];
    float y0 = (bits2f((u16)r[0]) - mean)*rstd*(1.0f+sc0.x) + sh0.x;
    float y1 = (bits2f((u16)r[1]) - mean)*rstd*(1.0f+sc0.y) + sh0.y;
    float y2 = (bits2f((u16)r[2]) - mean)*rstd*(1.0f+sc0.z) + sh0.z;
    float y3 = (bits2f((u16)r[3]) - mean)*rstd*(1.0f+sc0.w) + sh0.w;
    float y4 = (bits2f((u16)r[4]) - mean)*rstd*(1.0f+sc1.x) + sh1.x;
    float y5 = (bits2f((u16)r[5]) - mean)*rstd*(1.0f+sc1.y) + sh1.y;
    float y6 = (bits2f((u16)r[6]) - mean)*rstd*(1.0f+sc1.z) + sh1.z;
    float y7 = (bits2f((u16)r[7]) - mean)*rstd*(1.0f+sc1.w) + sh1.w;
    afr[ks] = pack8(y0,y1,y2,y3,y4,y5,y6,y7);
  }

  __syncthreads();   // chunk 0 staged + all waves ready

  // ---- main loop: 32 chunks of 32 hidden, double-buffered weights ----
  f32x4 acc2[16];
  #pragma unroll
  for (int nt = 0; nt < 16; ++nt) acc2[nt] = (f32x4){0.f,0.f,0.f,0.f};
  int buf = 0;
  #pragma unroll 1
  for (int c = 0; c < 32; ++c){
    if (c < 31){
      int cn = c + 1;
      #pragma unroll
      for (int i = 0; i < 8; ++i){
        int seg = wave*8 + i;
        const u16* src = (seg < 16)
            ? (w1f + (size_t)cn*8192 + (size_t)seg*512 + lane*8)
            : (w2f + (size_t)cn*8192 + (size_t)(seg-16)*512 + lane*8);
        stage16(src, &wbuf[buf^1][seg*512]);
      }
    }
    const u16* w1l = &wbuf[buf][0];
    const u16* w2l = &wbuf[buf][8192];
    f32x4 acc1[2];
    acc1[0] = (f32x4){0.f,0.f,0.f,0.f}; acc1[1] = (f32x4){0.f,0.f,0.f,0.f};
    #pragma unroll
    for (int ks = 0; ks < 8; ++ks){
      #pragma unroll
      for (int nt2 = 0; nt2 < 2; ++nt2){
        short8 bfr = *(const short8*)(w1l + (nt2*8 + ks)*512 + lane*8);
        acc1[nt2] = __builtin_amdgcn_mfma_f32_16x16x32_bf16(afr[ks], bfr, acc1[nt2], 0, 0, 0);
      }
    }
    __builtin_amdgcn_sched_barrier(0);
    #pragma unroll
    for (int nt2 = 0; nt2 < 2; ++nt2){
      int hid = nt2*16 + l15;
      float b1 = b1c[c*32 + hid];
      #pragma unroll
      for (int r = 0; r < 4; ++r)
        hs[mrow + quad*4 + r][hid] = f2bits(gelu_fast(acc1[nt2][r] + b1));
    }
    __builtin_amdgcn_sched_barrier(0);
    asm volatile("s_waitcnt lgkmcnt(0)" ::: "memory");
    __builtin_amdgcn_sched_barrier(0);
    short8 a2 = *(const short8*)&hs[mrow + l15][quad*8];
    #pragma unroll
    for (int nt = 0; nt < 16; ++nt){
      short8 bfr = *(const short8*)(w2l + nt*512 + lane*8);
      acc2[nt] = __builtin_amdgcn_mfma_f32_16x16x32_bf16(a2, bfr, acc2[nt], 0, 0, 0);
    }
    __syncthreads();
    buf ^= 1;
  }

  // ---- epilogue ----
  #pragma unroll
  for (int nt = 0; nt < 16; ++nt){
    int col = nt*16 + l15;
    float g = modp[1280 + col];
    float b2v = b2c[col];
    #pragma unroll
    for (int r = 0; r < 4; ++r){
      size_t o = ((size_t)(t0 + mrow + quad*4 + r))*256 + col;
      float resid = f ? bits2f(((const u16*)outv)[o]) : ((const float*)outv)[o];
      float y = resid + g*(acc2[nt][r] + b2v);
      if (f) ((u16*)outv)[o] = f2bits(y);
      else   ((float*)outv)[o] = y;
    }
  }
}

extern "C" void kernel_launch(void* const* d_in, const int* in_sizes, int n_in,
                              void* d_out, int out_size, void* d_ws, size_t ws_size,
                              hipStream_t stream){
  (void)n_in; (void)out_size;

  char* p = (char*)d_ws;
  auto alloc = [&](size_t bytes)->void*{
    void* r = (void*)p; p += (bytes + 255) & ~(size_t)255; return r;
  };

  int* flag = (int*)alloc(4);
  float* cin[28];
  cin[0] = nullptr;
  for (int i = 1; i < 28; ++i) cin[i] = (float*)alloc((size_t)in_sizes[i]*4);

  float* mod  = (float*)alloc((size_t)4*1536*4);
  float* lw   = (float*)alloc((size_t)128*4);
  float* redx = (float*)alloc((size_t)4*256*256*4);
  float* redy = (float*)alloc((size_t)4*128*256*4);
  float* tx   = (float*)alloc((size_t)4*256*256*4);
  float* hx   = (float*)alloc((size_t)4*256*256*4);
  float* uxb  = (float*)alloc((size_t)4*256*128*4);
  float* ty   = (float*)alloc((size_t)4*128*256*4);
  float* hy   = (float*)alloc((size_t)4*128*256*4);
  float* uyb  = (float*)alloc((size_t)4*128*128*4);
  float* qkx  = (float*)alloc((size_t)4*256*1024*4);
  float* qky  = (float*)alloc((size_t)4*128*1024*4);
  float* kTx  = (float*)alloc((size_t)4*8*64*256*4);   // 2MB
  float* kTy  = (float*)alloc((size_t)4*8*64*128*4);   // 1MB
  float* radx = (float*)alloc((size_t)8*256*256*4);
  float* rady = (float*)alloc((size_t)8*128*128*4);
  u16* kxb = (u16*)alloc((size_t)32*256*256*2);
  u16* kyb = (u16*)alloc((size_t)32*128*128*2);
  u16* w1f = (u16*)alloc((size_t)256*1024*2);
  u16* w2f = (u16*)alloc((size_t)1024*256*2);
  u16* WvT = (u16*)alloc((size_t)512*256*2);
  u16* WmT = (u16*)alloc((size_t)256*512*2);
  u16* um  = (u16*)alloc((size_t)NTOK*256*2);          // 67 MB

  // slots: merged mode needs 4 b's live in both slots (268 MB); fall back to
  // the per-b serial chain when the workspace is too small.
  size_t used = (size_t)(p - (char*)d_ws);
  int merged = (ws_size > used) && ((ws_size - used) >= (size_t)8*SLOT_ELE*2 + 65536);
  size_t slotBytes = (merged ? 4 : 1) * SLOT_ELE * 2;
  u16* slotV = (u16*)alloc(slotBytes);
  u16* slotP = (u16*)alloc(slotBytes);

  const void* u = d_in[0];

  k_detect<<<1, 1, 0, stream>>>(d_in[3], flag);
  for (int i = 1; i < 28; ++i){
    int n = in_sizes[i];
    int blocks = (n + 255)/256; if (blocks > 1024) blocks = 1024;
    k_cvt<<<blocks, 256, 0, stream>>>(d_in[i], cin[i], n, flag);
  }
  k_wprep<<<1024, 256, 0, stream>>>(cin[24], w1f, 8, 1024, 256*1024);
  k_wprep2<<<1024, 256, 0, stream>>>(cin[26], w2f);
  k_wtrans<<<512, 256, 0, stream>>>(cin[7],  WvT, 256, 512);   // to_v_w
  k_wtrans<<<512, 256, 0, stream>>>(cin[22], WmT, 512, 256);   // merge_w

  k_mod<<<24, 256, 0, stream>>>(cin[4], cin[5], cin[6], mod);
  k_lw<<<1, 128, 0, stream>>>(cin[1], lw);
  k_um2<<<NTOK/64, 256, 0, stream>>>(u, mod, um, flag);
  k_redx<<<1024, 256, 0, stream>>>(um, lw, redx);
  k_redy<<<512, 256, 0, stream>>>(um, redy);
  // bottleneck chains, x+y fused per stage
  gemm_row2<<<1536, 256, 0, stream>>>(redx, cin[8],  nullptr,  tx,  256, 256,
                                      redy, cin[13], nullptr,  ty,  256, 256, 1024, 0);
  gemm_row2<<<1536, 256, 0, stream>>>(tx,   cin[9],  cin[10],  hx,  256, 256,
                                      ty,   cin[14], cin[15],  hy,  256, 256, 1024, 1);
  gemm_row2<<<1536, 256, 0, stream>>>(hx,   cin[11], cin[12],  uxb, 256, 128,
                                      hy,   cin[16], cin[17],  uyb, 256, 128, 1024, 0);
  gemm_row2<<<1536, 256, 0, stream>>>(uxb,  cin[18], nullptr,  qkx, 128, 1024,
                                      uyb,  cin[19], nullptr,  qky, 128, 1024, 1024, 0);
  k_radial<<<(8*256*256)/256, 256, 0, stream>>>(cin[3], cin[20], radx, 256);
  k_radial<<<(8*128*128)/256, 256, 0, stream>>>(cin[2], cin[21], rady, 128);
  k_qkT<<<2048, 256, 0, stream>>>(qkx, kTx, 256);
  k_qkT<<<1024, 256, 0, stream>>>(qky, kTy, 128);
  k_attn2<<<4*8*256, 256, (64+8)*4, stream>>>(qkx, kTx, radx, kxb, 256);
  k_attn2<<<4*8*128, 128, (64+8)*4, stream>>>(qky, kTy, rady, kyb, 128);

  if (merged){
    // all 4 batches in flight; slotV/slotP hold [b][...] with stride SLOT_ELE
    k_v2    <<<2048, 256, 0, stream>>>(um, WvT, slotV, 0, SLOT_ELE);
    k_phi1b <<<2048, 256, 0, stream>>>(kyb, slotV, slotP, 0, SLOT_ELE);
    k_phi2b <<<2048, 256, 0, stream>>>(kxb, slotP, slotV, 0, SLOT_ELE); // vT dead
    k_gnb   <<<8192, 256, 0, stream>>>(slotV, slotP, 0, SLOT_ELE);      // phi dead
    k_mergeb<<<1024, 256, 0, stream>>>(slotP, WmT, cin[23], mod, u, d_out, flag, 0, SLOT_ELE);
  } else {
    for (int b = 0; b < 4; ++b){
      k_v2    <<<512, 256, 0, stream>>>(um, WvT, slotV, b, 0);
      k_phi1b <<<512, 256, 0, stream>>>(kyb, slotV, slotP, b, 0);
      k_phi2b <<<512, 256, 0, stream>>>(kxb, slotP, slotV, b, 0);
      k_gnb   <<<2048, 256, 0, stream>>>(slotV, slotP, b, 0);
      k_mergeb<<<256, 256, 0, stream>>>(slotP, WmT, cin[23], mod, u, d_out, flag, b, 0);
    }
  }
  k_ffn4<<<NTOK/64, 256, 0, stream>>>(mod, w1f, cin[25], w2f, cin[27], d_out, flag);
}

// Round 4
// 1452.351 us; speedup vs baseline: 2.0587x; 1.2370x over previous
//
#include <hip/hip_runtime.h>
#include <hip/hip_bf16.h>
#include <math.h>

// FADiTBlockS2: b=4, nlat=128, nlon=256, dim=256, H=8, DH=64, BNECK=128, NK=32
// Round 8: k_phi1b (379us, FETCH 530MB = 4x vT size) was a 2B/64B-line gather
// that fell out of L2 when the b-loop merged. Fix by layout:
//  - k_v3: v-proj with j-major token tiles + LDS C-tile transpose, emits
//    vA[h][(c*256+m)][j] (j fastest) with coalesced 16B stores
//  - k_phi1c: A-frag = contiguous short8 from vA (K=j contiguous); same math,
//    same phi output layout (phi2b unchanged)
//  - k_cvtall: 27 k_cvt launches -> 1 (by-value pointer table)

#define B_ 4
#define NLAT 128
#define NLON 256
#define NTOK (B_*NLAT*NLON)   // 131072
#define SLOT_ELE ((size_t)16777216)   // per-b slot elements (8h x 32768tok x 64c)

typedef __hip_bfloat16 bf16;
typedef unsigned short u16;
typedef __attribute__((ext_vector_type(8))) short short8;
typedef __attribute__((ext_vector_type(4))) float f32x4;

__device__ __forceinline__ float b2f(bf16 x){ return __bfloat162float(x); }
__device__ __forceinline__ bf16  f2b(float x){ return __float2bfloat16(x); }
__device__ __forceinline__ u16 f2bits(float x){
  bf16 h = __float2bfloat16(x); return *(u16*)&h;
}
__device__ __forceinline__ float bits2f(u16 u){
  union { unsigned int i; float f; } v; v.i = ((unsigned int)u) << 16; return v.f;
}
__device__ __forceinline__ float gelu_f(float x){
  float x3 = x*x*x;
  return 0.5f*x*(1.0f + tanhf(0.7978845608028654f*(x + 0.044715f*x3)));
}
// identity-exact fast gelu: tanh(t) = 1 - 2/(exp2(t*2/ln2)+1)
__device__ __forceinline__ float gelu_fast(float x){
  float t = 0.7978845608028654f*(x + 0.044715f*x*x*x);
  float e = __builtin_amdgcn_exp2f(t * 2.8853900817779268f);
  return x - x*__builtin_amdgcn_rcpf(e + 1.0f);
}
__device__ __forceinline__ float ldin(const void* p, size_t i, int flag){
  return flag ? b2f(((const bf16*)p)[i]) : ((const float*)p)[i];
}
__device__ __forceinline__ short4 pack4(float a, float b, float c, float d){
  short4 r; r.x = (short)f2bits(a); r.y = (short)f2bits(b);
  r.z = (short)f2bits(c); r.w = (short)f2bits(d); return r;
}
__device__ __forceinline__ short8 pack8(float a, float b, float c, float d,
                                        float e, float f, float g, float h){
  short8 r;
  r[0]=(short)f2bits(a); r[1]=(short)f2bits(b); r[2]=(short)f2bits(c); r[3]=(short)f2bits(d);
  r[4]=(short)f2bits(e); r[5]=(short)f2bits(f); r[6]=(short)f2bits(g); r[7]=(short)f2bits(h);
  return r;
}
// async global->LDS 16B: lds dest is wave-uniform base (+lane*16 by HW),
// global src is per-lane.
__device__ __forceinline__ void stage16(const u16* g, u16* l){
  __builtin_amdgcn_global_load_lds(
      (const __attribute__((address_space(1))) void*)g,
      (__attribute__((address_space(3))) void*)l, 16, 0, 0);
}

// ---------------- dtype detection: lon_diff[1] == 2*pi/256 -----------------
__global__ void k_detect(const void* lon_diff, int* flag){
  const float c = 0.02454369260617026f;
  float asF = ((const float*)lon_diff)[1];
  float asB = b2f(((const bf16*)lon_diff)[1]);
  float ef = fabsf(asF - c), eb = fabsf(asB - c);
  if (!isfinite(ef)) ef = 1e30f;
  *flag = (eb < ef) ? 1 : 0;   // 1 = bf16 buffers, 0 = f32 buffers
}

// ---------------- all-input convert in one launch --------------------------
struct CvtTab {
  const void* src[27];
  float* dst[27];
  int cum[28];
};
__global__ __launch_bounds__(256) void k_cvtall(CvtTab t, const int* __restrict__ flag,
                                                int total){
  int f = *flag;
  for (int i = blockIdx.x*256 + threadIdx.x; i < total; i += gridDim.x*256){
    int s = 0;
    while (i >= t.cum[s+1]) ++s;
    int off = i - t.cum[s];
    t.dst[s][off] = ldin(t.src[s], off, f);
  }
}

// ------- pack weight [K][N] f32 -> fragment-order bf16 ([nt][ks][lane][8]) -
__global__ __launch_bounds__(256) void k_wprep(const float* __restrict__ W,
                                               u16* __restrict__ wf,
                                               int KS, int ldn, int total){
  int gid = blockIdx.x*256 + threadIdx.x;
  if (gid >= total) return;
  int j = gid & 7; int lane = (gid >> 3) & 63; int rest = gid >> 9;
  int ks = rest % KS; int nt = rest / KS;
  int k = ks*32 + (lane >> 4)*8 + j;
  int n = nt*16 + (lane & 15);
  wf[gid] = f2bits(W[(size_t)k*ldn + n]);
}

// ------- w2 pack: [ksAll 0..31][nt 0..15][lane][8]; W2 is [1024][256] ------
__global__ __launch_bounds__(256) void k_wprep2(const float* __restrict__ W,
                                                u16* __restrict__ wf){
  int gid = blockIdx.x*256 + threadIdx.x;   // 262144 total
  int j = gid & 7; int lane = (gid >> 3) & 63; int rest = gid >> 9;
  int nt = rest & 15; int ksAll = rest >> 4;
  int k = ksAll*32 + (lane >> 4)*8 + j;
  int n = nt*16 + (lane & 15);
  wf[gid] = f2bits(W[(size_t)k*256 + n]);
}

// ------- transposed bf16 copy: WT[n][k] = W[k][n] ---------------------------
__global__ __launch_bounds__(256) void k_wtrans(const float* __restrict__ W,
                                                u16* __restrict__ WT, int K, int N){
  int gid = blockIdx.x*256 + threadIdx.x;
  if (gid >= K*N) return;
  int k = gid % K, n = gid / K;
  WT[(size_t)n*K + k] = f2bits(W[(size_t)k*N + n]);
}

// ---------------- mod = scalar_cond @ adaLN_w + adaLN_b  (4 x 1536) --------
__global__ __launch_bounds__(256) void k_mod(const float* __restrict__ sc,
                                             const float* __restrict__ w,
                                             const float* __restrict__ bias,
                                             float* __restrict__ mod){
  int gid = blockIdx.x*256 + threadIdx.x;
  int s = gid / 1536, j = gid % 1536;
  float acc = bias[j];
  for (int c = 0; c < 256; ++c) acc += sc[s*256+c] * w[c*1536+j];
  mod[gid] = acc;
}

// ---------------- lw = cos(lat)/mean(cos(lat)) -----------------------------
__global__ __launch_bounds__(128) void k_lw(const float* __restrict__ lat,
                                            float* __restrict__ lw){
  __shared__ float red[128];
  int i = threadIdx.x;
  float cv = cosf(lat[i]);
  red[i] = cv; __syncthreads();
  for (int s = 64; s > 0; s >>= 1){ if (i < s) red[i] += red[i+s]; __syncthreads(); }
  float mean = red[0] * (1.0f/128.0f);
  lw[i] = cv / mean;
}

// ------- um = LN(u)*(1+sc_msa)+sh_msa : 64 tokens/block, coalesced ---------
__global__ __launch_bounds__(256) void k_um2(const void* __restrict__ u,
                                             const float* __restrict__ mod,
                                             u16* __restrict__ um,
                                             const int* __restrict__ flag){
  __shared__ u16 tile[64][264];
  __shared__ float r1[64][4], r2[64][4], mv[64], rs[64];
  __shared__ float ssh[256], ssc[256];
  int f = *flag; int tid = threadIdx.x;
  int t0 = blockIdx.x*64; int b = t0 >> 15;
  ssh[tid] = mod[b*1536 + tid];
  ssc[tid] = mod[b*1536 + 256 + tid];
  // phase 1: coalesced load -> bf16 tile
  for (int it = 0; it < 16; ++it){
    int idx = it*256 + tid;       // 4096 vec4 groups
    int tok = idx >> 6, c4 = idx & 63;
    short4 v4;
    if (f){
      v4 = *(const short4*)((const bf16*)u + ((size_t)(t0+tok))*256 + c4*4);
    } else {
      float4 fv = ((const float4*)u)[((size_t)(t0+tok))*64 + c4];
      v4 = pack4(fv.x, fv.y, fv.z, fv.w);
    }
    *(short4*)&tile[tok][c4*4] = v4;
  }
  __syncthreads();
  // phase 2: stats (4 threads per token)
  {
    int tok = tid >> 2, part = tid & 3;
    float s1 = 0.f, s2 = 0.f;
    for (int c4 = 0; c4 < 16; ++c4){
      short4 v4 = *(const short4*)&tile[tok][part*64 + c4*4];
      float a = bits2f((u16)v4.x), bb = bits2f((u16)v4.y),
            c = bits2f((u16)v4.z), d = bits2f((u16)v4.w);
      s1 += a+bb+c+d; s2 += a*a+bb*bb+c*c+d*d;
    }
    r1[tok][part] = s1; r2[tok][part] = s2;
  }
  __syncthreads();
  if ((tid & 3) == 0){
    int tok = tid >> 2;
    float a1 = r1[tok][0]+r1[tok][1]+r1[tok][2]+r1[tok][3];
    float a2 = r2[tok][0]+r2[tok][1]+r2[tok][2]+r2[tok][3];
    float mean = a1*(1.0f/256.0f);
    float var = a2*(1.0f/256.0f) - mean*mean;
    mv[tok] = mean; rs[tok] = rsqrtf(var + 1e-5f);
  }
  __syncthreads();
  // phase 3: modulate + coalesced store
  for (int it = 0; it < 16; ++it){
    int idx = it*256 + tid;
    int tok = idx >> 6, c4 = idx & 63;
    float mean = mv[tok], rstd = rs[tok];
    short4 v4 = *(const short4*)&tile[tok][c4*4];
    float y[4]; u16 raw[4] = {(u16)v4.x,(u16)v4.y,(u16)v4.z,(u16)v4.w};
    #pragma unroll
    for (int p = 0; p < 4; ++p){
      int c = c4*4 + p;
      y[p] = (bits2f(raw[p]) - mean)*rstd*(1.0f + ssc[c]) + ssh[c];
    }
    *(short4*)(um + ((size_t)(t0+tok))*256 + c4*4) = pack4(y[0],y[1],y[2],y[3]);
  }
}

// ---------------- redx[b,l,c] = (1/128) * sum_i um[b,i,l,c]*lw[i] ----------
__global__ __launch_bounds__(256) void k_redx(const u16* __restrict__ um,
                                              const float* __restrict__ lw,
                                              float* __restrict__ redx){
  __shared__ float lws[128];
  int tid = threadIdx.x;
  if (tid < 128) lws[tid] = lw[tid];
  __syncthreads();
  int gid = blockIdx.x*256 + tid;
  int c = gid & 255; int l = (gid >> 8) & 255; int b = gid >> 16;
  float acc = 0.0f;
  for (int i = 0; i < 128; ++i)
    acc += bits2f(um[(((size_t)(b*128 + i)*256 + l)*256) + c]) * lws[i];
  redx[gid] = acc * (1.0f/128.0f);
}

__global__ __launch_bounds__(256) void k_redy(const u16* __restrict__ um,
                                              float* __restrict__ redy){
  int gid = blockIdx.x*256 + threadIdx.x;
  int c = gid & 255; int i = (gid >> 8) & 127; int b = gid >> 15;
  float acc = 0.0f;
  for (int l = 0; l < 256; ++l)
    acc += bits2f(um[(((size_t)(b*128 + i)*256 + l)*256) + c]);
  redy[gid] = acc * (1.0f/256.0f);
}

// ------- dual row GEMM: x-chain rows [0,nbx), y-chain rows [nbx,nbx+nby) ---
__global__ __launch_bounds__(256) void gemm_row2(
    const float* __restrict__ Ax, const float* __restrict__ Wx,
    const float* __restrict__ bx, float* __restrict__ Cx, int Kx, int Nx,
    const float* __restrict__ Ay, const float* __restrict__ Wy,
    const float* __restrict__ by, float* __restrict__ Cy, int Ky, int Ny,
    int nbx, int act){
  __shared__ float As[256];
  int bid = blockIdx.x; int tid = threadIdx.x;
  const float* A; const float* W; const float* bias; float* C; int K, N, r;
  if (bid < nbx){ A=Ax; W=Wx; bias=bx; C=Cx; K=Kx; N=Nx; r=bid; }
  else          { A=Ay; W=Wy; bias=by; C=Cy; K=Ky; N=Ny; r=bid-nbx; }
  for (int k = tid; k < K; k += 256) As[k] = A[(size_t)r*K + k];
  __syncthreads();
  for (int n = tid; n < N; n += 256){
    float a0=0.f, a1=0.f, a2=0.f, a3=0.f;
    for (int k = 0; k < K; k += 4){
      a0 += As[k+0]*W[(size_t)(k+0)*N + n];
      a1 += As[k+1]*W[(size_t)(k+1)*N + n];
      a2 += As[k+2]*W[(size_t)(k+2)*N + n];
      a3 += As[k+3]*W[(size_t)(k+3)*N + n];
    }
    float acc = (a0+a1)+(a2+a3) + (bias ? bias[n] : 0.0f);
    if (act == 1) acc = gelu_f(acc);
    C[(size_t)r*N + n] = acc;
  }
}

// ---------------- radial[h,i,j] ---------------------------------------------
__global__ __launch_bounds__(256) void k_radial(const float* __restrict__ d,
                                                const float* __restrict__ w,
                                                float* __restrict__ rad, int n){
  int gid = blockIdx.x*256 + threadIdx.x;
  int nn = n*n;
  int h = gid / nn; int rem = gid % nn;
  float dv = d[rem];
  float safe = fmaxf(dv, 1e-6f);
  float acc = 0.0f;
  for (int k = 0; k < 32; ++k){
    float nk = (float)(k+1);
    float basis = (dv > 1e-6f) ? (sinf(dv*nk)/safe) : nk;
    acc += basis * w[k*8 + h];
  }
  rad[gid] = acc;
}

// ------- kT[((b*8+h)*64+d)][j] = qk[(b*n+j)][512+h*64+d]  (coalesced j) ----
__global__ __launch_bounds__(256) void k_qkT(const float* __restrict__ qk,
                                             float* __restrict__ kT, int n){
  int gid = blockIdx.x*256 + threadIdx.x;   // 4*8*64*n total
  int j = gid % n; int rest = gid / n;
  int d = rest & 63; int bh = rest >> 6;
  int b = bh >> 3, h = bh & 7;
  kT[gid] = qk[((size_t)(b*n + j))*1024 + 512 + h*64 + d];
}

// ------- attention weights -> bf16 rows [bh][i][j], coalesced K reads ------
__global__ __launch_bounds__(256) void k_attn2(const float* __restrict__ qk,
                                               const float* __restrict__ kT,
                                               const float* __restrict__ rad,
                                               u16* __restrict__ kout, int n){
  extern __shared__ float sm[];   // qs[64] + red[8]
  float* qs = sm; float* red = sm + 64;
  int j = threadIdx.x;
  int bid = blockIdx.x; int i = bid % n; int h = (bid / n) & 7; int b = bid / (n*8);
  if (j < 64) qs[j] = qk[((size_t)(b*n + i))*1024 + h*64 + j];
  __syncthreads();
  const float* kcol = kT + ((size_t)((b*8 + h)*64))*n + j;
  float dot = 0.0f;
  #pragma unroll 8
  for (int d0 = 0; d0 < 64; ++d0) dot += qs[d0]*kcol[(size_t)d0*n];
  float s = dot * rad[((size_t)(h*n + i))*n + j];
  // block max: wave shuffle + tiny LDS cross-wave
  float m = s;
  #pragma unroll
  for (int off = 32; off; off >>= 1) m = fmaxf(m, __shfl_xor(m, off));
  int wv = j >> 6, nw = n >> 6;
  if ((j & 63) == 0) red[wv] = m;
  __syncthreads();
  m = red[0];
  for (int w = 1; w < nw; ++w) m = fmaxf(m, red[w]);
  float e = __builtin_amdgcn_exp2f((s - m)*1.44269504088896f);
  float t = e;
  #pragma unroll
  for (int off = 32; off; off >>= 1) t += __shfl_xor(t, off);
  if ((j & 63) == 0) red[4 + wv] = t;
  __syncthreads();
  t = 0.0f;
  for (int w = 0; w < nw; ++w) t += red[4 + w];
  kout[(size_t)bid*n + j] = f2bits(e / t);
}

// ======== k_v3: v-proj, j-major tiles, LDS-transposed output ===============
// M=512 hc, N=64 tokens {tok = j*256+m, j in [jt*64, jt*64+64), m fixed}, K=256.
// Output: vA[h][(c*256+m)][j]  (j fastest, coalesced 16B stores).
__global__ __launch_bounds__(256, 2) void k_v3(const u16* __restrict__ um,
                                               const u16* __restrict__ WvT,
                                               u16* __restrict__ vA,
                                               int b0, size_t bstr){
  __shared__ __align__(16) u16 T[512][72];   // 72 KB, row stride 144B (16-mult)
  int tid = threadIdx.x;
  int wave = tid>>6, lane = tid&63, quad = lane>>4, l15 = lane&15;
  int bid = blockIdx.x;
  int b = b0 + (bid >> 9);
  int rem = bid & 511;
  int m = rem & 255, jt = rem >> 8;
  const u16* umb = um + ((size_t)b*32768)*256;
  f32x4 acc[8][4];
  #pragma unroll
  for (int mt = 0; mt < 8; ++mt)
    #pragma unroll
    for (int nt = 0; nt < 4; ++nt) acc[mt][nt] = (f32x4){0.f,0.f,0.f,0.f};
  for (int ks = 0; ks < 8; ++ks){
    short8 bfr[4];
    #pragma unroll
    for (int nt = 0; nt < 4; ++nt){
      int j = jt*64 + nt*16 + l15;
      bfr[nt] = *(const short8*)(umb + ((size_t)j*256 + m)*256 + ks*32 + quad*8);
    }
    #pragma unroll
    for (int mt = 0; mt < 8; ++mt){
      short8 a = *(const short8*)(WvT + (size_t)((wave*8+mt)*16 + l15)*256 + ks*32 + quad*8);
      #pragma unroll
      for (int nt = 0; nt < 4; ++nt)
        acc[mt][nt] = __builtin_amdgcn_mfma_f32_16x16x32_bf16(a, bfr[nt], acc[mt][nt], 0, 0, 0);
    }
  }
  // C-tile -> LDS (transpose hc x j')
  #pragma unroll
  for (int mt = 0; mt < 8; ++mt){
    int hc0 = (wave*8+mt)*16 + quad*4;
    #pragma unroll
    for (int nt = 0; nt < 4; ++nt){
      int jp = nt*16 + l15;
      T[hc0+0][jp] = f2bits(acc[mt][nt][0]);
      T[hc0+1][jp] = f2bits(acc[mt][nt][1]);
      T[hc0+2][jp] = f2bits(acc[mt][nt][2]);
      T[hc0+3][jp] = f2bits(acc[mt][nt][3]);
    }
  }
  __syncthreads();
  // coalesced store: rows (h,c) of 64 j values (128B), 16B per lane
  u16* vAb = vA + (size_t)(b - b0)*bstr;
  for (int it = 0; it < 16; ++it){
    int idx = it*256 + tid;          // 4096 units of 8 u16
    int g = idx & 7, hc = idx >> 3;
    short8 v8 = *(const short8*)&T[hc][g*8];
    int h = hc >> 6, c = hc & 63;
    *(short8*)(vAb + (size_t)h*2097152 + ((size_t)c*256 + m)*128 + jt*64 + g*8) = v8;
  }
}

// ======== k_phi1c: C^T. M=(c,m) per block c fixed, N=i 128, K=j 128 ========
// A = contiguous vA rows [cm][j], B = ky rows. Out: phi[h][i][c*256+m] (as before)
__global__ __launch_bounds__(256) void k_phi1c(const u16* __restrict__ kyb,
                                               const u16* __restrict__ vA,
                                               u16* __restrict__ phi,
                                               int b0, size_t bstr){
  int tid = threadIdx.x;
  int wave = tid>>6, lane = tid&63, quad = lane>>4, l15 = lane&15;
  int bid = blockIdx.x;
  int b = b0 + (bid >> 9);
  int rem = bid & 511; int mblk = rem & 63, h = rem >> 6;
  int m0 = mblk*256;
  const u16* vAh = vA + (size_t)(b - b0)*bstr + (size_t)h*2097152;
  u16* phib = phi + (size_t)(b - b0)*bstr;
  const u16* kyh = kyb + (size_t)(b*8+h)*16384;
  f32x4 acc[4][8];
  #pragma unroll
  for (int mt = 0; mt < 4; ++mt)
    #pragma unroll
    for (int nt = 0; nt < 8; ++nt) acc[mt][nt] = (f32x4){0.f,0.f,0.f,0.f};
  for (int ks = 0; ks < 4; ++ks){
    short8 bfr[8];
    #pragma unroll
    for (int nt = 0; nt < 8; ++nt)
      bfr[nt] = *(const short8*)(kyh + (size_t)(nt*16 + l15)*128 + ks*32 + quad*8);
    #pragma unroll
    for (int mt = 0; mt < 4; ++mt){
      int cm = m0 + (wave*4+mt)*16 + l15;
      short8 a = *(const short8*)(vAh + (size_t)cm*128 + ks*32 + quad*8);
      #pragma unroll
      for (int nt = 0; nt < 8; ++nt)
        acc[mt][nt] = __builtin_amdgcn_mfma_f32_16x16x32_bf16(a, bfr[nt], acc[mt][nt], 0, 0, 0);
    }
  }
  #pragma unroll
  for (int mt = 0; mt < 4; ++mt){
    int cmr = m0 + (wave*4+mt)*16 + quad*4;
    #pragma unroll
    for (int nt = 0; nt < 8; ++nt){
      int i = nt*16 + l15;
      *(short4*)(phib + (size_t)h*2097152 + (size_t)i*16384 + cmr)
        = pack4(acc[mt][nt][0], acc[mt][nt][1], acc[mt][nt][2], acc[mt][nt][3]);
    }
  }
}

// ======== k_phi2b: M=(i,c) 8192, N=l 256, K=m 256 ==========================
__global__ __launch_bounds__(256) void k_phi2b(const u16* __restrict__ kxb,
                                               const u16* __restrict__ phi,
                                               u16* __restrict__ OUTt,
                                               int b0, size_t bstr){
  int tid = threadIdx.x;
  int wave = tid>>6, lane = tid&63, quad = lane>>4, l15 = lane&15;
  int bid = blockIdx.x;
  int b = b0 + (bid >> 9);
  int rem = bid & 511; int mblk = rem & 63, h = rem >> 6;
  int m0 = mblk*128;
  int mhalf = (wave&1)*4, nhalf = (wave>>1)*8;
  const u16* ph = phi + (size_t)(b - b0)*bstr + (size_t)h*2097152;
  u16* OUTb = OUTt + (size_t)(b - b0)*bstr;
  const u16* kxh = kxb + (size_t)(b*8+h)*65536;
  f32x4 acc[4][8];
  #pragma unroll
  for (int mt = 0; mt < 4; ++mt)
    #pragma unroll
    for (int nt = 0; nt < 8; ++nt) acc[mt][nt] = (f32x4){0.f,0.f,0.f,0.f};
  for (int ks = 0; ks < 8; ++ks){
    short8 bfr[8];
    #pragma unroll
    for (int nt = 0; nt < 8; ++nt)
      bfr[nt] = *(const short8*)(kxh + (size_t)((nhalf+nt)*16 + l15)*256 + ks*32 + quad*8);
    #pragma unroll
    for (int mt = 0; mt < 4; ++mt){
      int m2 = m0 + (mhalf+mt)*16 + l15;
      short8 a = *(const short8*)(ph + (size_t)m2*256 + ks*32 + quad*8);
      #pragma unroll
      for (int nt = 0; nt < 8; ++nt)
        acc[mt][nt] = __builtin_amdgcn_mfma_f32_16x16x32_bf16(a, bfr[nt], acc[mt][nt], 0, 0, 0);
    }
  }
  #pragma unroll
  for (int mt = 0; mt < 4; ++mt){
    int m2r = m0 + (mhalf+mt)*16 + quad*4;
    #pragma unroll
    for (int nt = 0; nt < 8; ++nt){
      int l = (nhalf+nt)*16 + l15;
      *(short4*)(OUTb + (size_t)h*2097152 + (size_t)l*8192 + m2r)
        = pack4(acc[mt][nt][0], acc[mt][nt][1], acc[mt][nt][2], acc[mt][nt][3]);
    }
  }
}

// ======== k_gnb: GroupNorm over 64-c groups, coalesced ======================
__global__ __launch_bounds__(256) void k_gnb(const u16* __restrict__ OUTt,
                                             u16* __restrict__ gn,
                                             int b0, size_t bstr){
  int tid = threadIdx.x;
  int bid = blockIdx.x;
  int bi = bid >> 11;
  int rem = bid & 2047; int l = rem & 255, h = rem >> 8;
  int i = tid >> 1, half = tid & 1;
  const u16* src = OUTt + (size_t)bi*bstr + (size_t)h*2097152 + (size_t)l*8192 + i*64 + half*32;
  float v[32]; float s1 = 0.f, s2 = 0.f;
  #pragma unroll
  for (int c4 = 0; c4 < 8; ++c4){
    short4 v4 = *(const short4*)(src + c4*4);
    v[c4*4+0] = bits2f((u16)v4.x); v[c4*4+1] = bits2f((u16)v4.y);
    v[c4*4+2] = bits2f((u16)v4.z); v[c4*4+3] = bits2f((u16)v4.w);
  }
  #pragma unroll
  for (int c = 0; c < 32; ++c){ s1 += v[c]; s2 += v[c]*v[c]; }
  s1 += __shfl_xor(s1, 1); s2 += __shfl_xor(s2, 1);
  float mean = s1*(1.0f/64.0f);
  float var = s2*(1.0f/64.0f) - mean*mean;
  float rstd = rsqrtf(var + 1e-6f);
  u16* dst = gn + (size_t)bi*bstr + ((size_t)(i*256 + l))*512 + h*64 + half*32;
  #pragma unroll
  for (int c4 = 0; c4 < 8; ++c4)
    *(short4*)(dst + c4*4) = pack4((v[c4*4+0]-mean)*rstd, (v[c4*4+1]-mean)*rstd,
                                   (v[c4*4+2]-mean)*rstd, (v[c4*4+3]-mean)*rstd);
}

// ======== k_mergeb: C^T. M=d 256, N=128 tokens, K=512 ======================
__global__ __launch_bounds__(256) void k_mergeb(const u16* __restrict__ gn,
                                                const u16* __restrict__ WmT,
                                                const float* __restrict__ biasm,
                                                const float* __restrict__ mod,
                                                const void* __restrict__ u,
                                                void* __restrict__ outv,
                                                const int* __restrict__ flag,
                                                int b0, size_t bstr){
  __shared__ float smg[256], sbb[256];
  int f = *flag;
  int tid = threadIdx.x;
  int bid = blockIdx.x;
  int b = b0 + (bid >> 8);
  int t0 = (bid & 255)*128;
  smg[tid] = mod[b*1536 + 512 + tid];
  sbb[tid] = biasm[tid];
  __syncthreads();
  int wave = tid>>6, lane = tid&63, quad = lane>>4, l15 = lane&15;
  const u16* gnb = gn + (size_t)(b - b0)*bstr;
  int nt0 = wave*2;
  f32x4 acc[16][2];
  #pragma unroll
  for (int mt = 0; mt < 16; ++mt){ acc[mt][0] = (f32x4){0.f,0.f,0.f,0.f}; acc[mt][1] = (f32x4){0.f,0.f,0.f,0.f}; }
  for (int ks = 0; ks < 16; ++ks){
    short8 bfr[2];
    #pragma unroll
    for (int nti = 0; nti < 2; ++nti){
      int tok = t0 + (nt0+nti)*16 + l15;
      bfr[nti] = *(const short8*)(gnb + (size_t)tok*512 + ks*32 + quad*8);
    }
    #pragma unroll
    for (int mt = 0; mt < 16; ++mt){
      short8 a = *(const short8*)(WmT + (size_t)(mt*16 + l15)*512 + ks*32 + quad*8);
      #pragma unroll
      for (int nti = 0; nti < 2; ++nti)
        acc[mt][nti] = __builtin_amdgcn_mfma_f32_16x16x32_bf16(a, bfr[nti], acc[mt][nti], 0, 0, 0);
    }
  }
  #pragma unroll
  for (int mt = 0; mt < 16; ++mt){
    int d0 = mt*16 + quad*4;
    #pragma unroll
    for (int nti = 0; nti < 2; ++nti){
      int tok = t0 + (nt0+nti)*16 + l15;
      size_t o = ((size_t)b*32768 + tok)*256 + d0;
      float r0,r1,r2,r3;
      if (f){
        short4 rv = *(const short4*)((const bf16*)u + o);
        r0 = bits2f((u16)rv.x); r1 = bits2f((u16)rv.y); r2 = bits2f((u16)rv.z); r3 = bits2f((u16)rv.w);
      } else {
        float4 rv = *(const float4*)((const float*)u + o);
        r0 = rv.x; r1 = rv.y; r2 = rv.z; r3 = rv.w;
      }
      float y0 = r0 + smg[d0+0]*(acc[mt][nti][0] + sbb[d0+0]);
      float y1 = r1 + smg[d0+1]*(acc[mt][nti][1] + sbb[d0+1]);
      float y2 = r2 + smg[d0+2]*(acc[mt][nti][2] + sbb[d0+2]);
      float y3 = r3 + smg[d0+3]*(acc[mt][nti][3] + sbb[d0+3]);
      if (f) *(short4*)((bf16*)outv + o) = pack4(y0,y1,y2,y3);
      else   *(float4*)((float*)outv + o) = (float4){y0,y1,y2,y3};
    }
  }
}

// ======== k_ffn4: LDS-staged weights, 2-phase pipeline, per-wave LN ========
__global__ __launch_bounds__(256, 2) void k_ffn4(
    const float* __restrict__ mod,
    const u16* __restrict__ w1f,
    const float* __restrict__ b1c,
    const u16* __restrict__ w2f,
    const float* __restrict__ b2c,
    void* __restrict__ outv,
    const int* __restrict__ flag){
  __shared__ __align__(16) u16 wbuf[2][16384];   // 2 x 32KB
  __shared__ __align__(16) u16 hs[64][40];       // per-wave 16 rows x 32 (+8 pad)
  int f = *flag;
  int tid = threadIdx.x;
  int wave = tid>>6, lane = tid&63, quad = lane>>4, l15 = lane&15;
  int mrow = wave*16;
  int t0 = blockIdx.x*64;
  int bb = t0 >> 15;
  const float* modp = mod + bb*1536;
  size_t rowbase = ((size_t)(t0 + mrow + l15))*256;

  // ---- stage chunk 0 into wbuf[0] (async; overlaps the LN below) ----
  {
    #pragma unroll
    for (int i = 0; i < 8; ++i){
      int seg = wave*8 + i;
      const u16* src = (seg < 16)
          ? (w1f + (size_t)seg*512 + lane*8)
          : (w2f + (size_t)(seg-16)*512 + lane*8);
      stage16(src, &wbuf[0][seg*512]);
    }
  }

  // ---- LN in registers ----
  short8 afr[8];
  float s1 = 0.f, s2 = 0.f;
  #pragma unroll
  for (int ks = 0; ks < 8; ++ks){
    int c0 = ks*32 + quad*8;
    float v0,v1,v2,v3,v4,v5,v6,v7;
    if (f){
      short8 r = *(const short8*)((const bf16*)outv + rowbase + c0);
      afr[ks] = r;
      v0 = bits2f((u16)r[0]); v1 = bits2f((u16)r[1]); v2 = bits2f((u16)r[2]); v3 = bits2f((u16)r[3]);
      v4 = bits2f((u16)r[4]); v5 = bits2f((u16)r[5]); v6 = bits2f((u16)r[6]); v7 = bits2f((u16)r[7]);
    } else {
      float4 fa = *(const float4*)((const float*)outv + rowbase + c0);
      float4 fb = *(const float4*)((const float*)outv + rowbase + c0 + 4);
      v0=fa.x; v1=fa.y; v2=fa.z; v3=fa.w; v4=fb.x; v5=fb.y; v6=fb.z; v7=fb.w;
      afr[ks] = pack8(v0,v1,v2,v3,v4,v5,v6,v7);
    }
    s1 += v0+v1+v2+v3+v4+v5+v6+v7;
    s2 += v0*v0+v1*v1+v2*v2+v3*v3+v4*v4+v5*v5+v6*v6+v7*v7;
  }
  s1 += __shfl_xor(s1, 16); s1 += __shfl_xor(s1, 32);
  s2 += __shfl_xor(s2, 16); s2 += __shfl_xor(s2, 32);
  float mean = s1*(1.0f/256.0f);
  float var = s2*(1.0f/256.0f) - mean*mean;
  float rstd = rsqrtf(var + 1e-5f);
  #pragma unroll
  for (int ks = 0; ks < 8; ++ks){
    int c0 = ks*32 + quad*8;
    float4 sh0 = *(const float4*)&modp[768 + c0];
    float4 sh1 = *(const float4*)&modp[768 + c0 + 4];
    float4 sc0 = *(const float4*)&modp[1024 + c0];
    float4 sc1 = *(const float4*)&modp[1024 + c0 + 4];
    short8 r = afr[ks];
    float y0 = (bits2f((u16)r[0]) - mean)*rstd*(1.0f+sc0.x) + sh0.x;
    float y1 = (bits2f((u16)r[1]) - mean)*rstd*(1.0f+sc0.y) + sh0.y;
    float y2 = (bits2f((u16)r[2]) - mean)*rstd*(1.0f+sc0.z) + sh0.z;
    float y3 = (bits2f((u16)r[3]) - mean)*rstd*(1.0f+sc0.w) + sh0.w;
    float y4 = (bits2f((u16)r[4]) - mean)*rstd*(1.0f+sc1.x) + sh1.x;
    float y5 = (bits2f((u16)r[5]) - mean)*rstd*(1.0f+sc1.y) + sh1.y;
    float y6 = (bits2f((u16)r[6]) - mean)*rstd*(1.0f+sc1.z) + sh1.z;
    float y7 = (bits2f((u16)r[7]) - mean)*rstd*(1.0f+sc1.w) + sh1.w;
    afr[ks] = pack8(y0,y1,y2,y3,y4,y5,y6,y7);
  }

  __syncthreads();   // chunk 0 staged + all waves ready

  // ---- main loop: 32 chunks of 32 hidden, double-buffered weights ----
  f32x4 acc2[16];
  #pragma unroll
  for (int nt = 0; nt < 16; ++nt) acc2[nt] = (f32x4){0.f,0.f,0.f,0.f};
  int buf = 0;
  #pragma unroll 1
  for (int c = 0; c < 32; ++c){
    if (c < 31){
      int cn = c + 1;
      #pragma unroll
      for (int i = 0; i < 8; ++i){
        int seg = wave*8 + i;
        const u16* src = (seg < 16)
            ? (w1f + (size_t)cn*8192 + (size_t)seg*512 + lane*8)
            : (w2f + (size_t)cn*8192 + (size_t)(seg-16)*512 + lane*8);
        stage16(src, &wbuf[buf^1][seg*512]);
      }
    }
    const u16* w1l = &wbuf[buf][0];
    const u16* w2l = &wbuf[buf][8192];
    f32x4 acc1[2];
    acc1[0] = (f32x4){0.f,0.f,0.f,0.f}; acc1[1] = (f32x4){0.f,0.f,0.f,0.f};
    #pragma unroll
    for (int ks = 0; ks < 8; ++ks){
      #pragma unroll
      for (int nt2 = 0; nt2 < 2; ++nt2){
        short8 bfr = *(const short8*)(w1l + (nt2*8 + ks)*512 + lane*8);
        acc1[nt2] = __builtin_amdgcn_mfma_f32_16x16x32_bf16(afr[ks], bfr, acc1[nt2], 0, 0, 0);
      }
    }
    __builtin_amdgcn_sched_barrier(0);
    #pragma unroll
    for (int nt2 = 0; nt2 < 2; ++nt2){
      int hid = nt2*16 + l15;
      float b1 = b1c[c*32 + hid];
      #pragma unroll
      for (int r = 0; r < 4; ++r)
        hs[mrow + quad*4 + r][hid] = f2bits(gelu_fast(acc1[nt2][r] + b1));
    }
    __builtin_amdgcn_sched_barrier(0);
    asm volatile("s_waitcnt lgkmcnt(0)" ::: "memory");
    __builtin_amdgcn_sched_barrier(0);
    short8 a2 = *(const short8*)&hs[mrow + l15][quad*8];
    #pragma unroll
    for (int nt = 0; nt < 16; ++nt){
      short8 bfr = *(const short8*)(w2l + nt*512 + lane*8);
      acc2[nt] = __builtin_amdgcn_mfma_f32_16x16x32_bf16(a2, bfr, acc2[nt], 0, 0, 0);
    }
    __syncthreads();
    buf ^= 1;
  }

  // ---- epilogue ----
  #pragma unroll
  for (int nt = 0; nt < 16; ++nt){
    int col = nt*16 + l15;
    float g = modp[1280 + col];
    float b2v = b2c[col];
    #pragma unroll
    for (int r = 0; r < 4; ++r){
      size_t o = ((size_t)(t0 + mrow + quad*4 + r))*256 + col;
      float resid = f ? bits2f(((const u16*)outv)[o]) : ((const float*)outv)[o];
      float y = resid + g*(acc2[nt][r] + b2v);
      if (f) ((u16*)outv)[o] = f2bits(y);
      else   ((float*)outv)[o] = y;
    }
  }
}

extern "C" void kernel_launch(void* const* d_in, const int* in_sizes, int n_in,
                              void* d_out, int out_size, void* d_ws, size_t ws_size,
                              hipStream_t stream){
  (void)n_in; (void)out_size;

  char* p = (char*)d_ws;
  auto alloc = [&](size_t bytes)->void*{
    void* r = (void*)p; p += (bytes + 255) & ~(size_t)255; return r;
  };

  int* flag = (int*)alloc(4);
  float* cin[28];
  cin[0] = nullptr;
  for (int i = 1; i < 28; ++i) cin[i] = (float*)alloc((size_t)in_sizes[i]*4);

  float* mod  = (float*)alloc((size_t)4*1536*4);
  float* lw   = (float*)alloc((size_t)128*4);
  float* redx = (float*)alloc((size_t)4*256*256*4);
  float* redy = (float*)alloc((size_t)4*128*256*4);
  float* tx   = (float*)alloc((size_t)4*256*256*4);
  float* hx   = (float*)alloc((size_t)4*256*256*4);
  float* uxb  = (float*)alloc((size_t)4*256*128*4);
  float* ty   = (float*)alloc((size_t)4*128*256*4);
  float* hy   = (float*)alloc((size_t)4*128*256*4);
  float* uyb  = (float*)alloc((size_t)4*128*128*4);
  float* qkx  = (float*)alloc((size_t)4*256*1024*4);
  float* qky  = (float*)alloc((size_t)4*128*1024*4);
  float* kTx  = (float*)alloc((size_t)4*8*64*256*4);   // 2MB
  float* kTy  = (float*)alloc((size_t)4*8*64*128*4);   // 1MB
  float* radx = (float*)alloc((size_t)8*256*256*4);
  float* rady = (float*)alloc((size_t)8*128*128*4);
  u16* kxb = (u16*)alloc((size_t)32*256*256*2);
  u16* kyb = (u16*)alloc((size_t)32*128*128*2);
  u16* w1f = (u16*)alloc((size_t)256*1024*2);
  u16* w2f = (u16*)alloc((size_t)1024*256*2);
  u16* WvT = (u16*)alloc((size_t)512*256*2);
  u16* WmT = (u16*)alloc((size_t)256*512*2);
  u16* um  = (u16*)alloc((size_t)NTOK*256*2);          // 67 MB

  // slots: merged mode needs 4 b's live in both slots (268 MB); fall back to
  // the per-b serial chain when the workspace is too small.
  size_t used = (size_t)(p - (char*)d_ws);
  int merged = (ws_size > used) && ((ws_size - used) >= (size_t)8*SLOT_ELE*2 + 65536);
  size_t slotBytes = (merged ? 4 : 1) * SLOT_ELE * 2;
  u16* slotV = (u16*)alloc(slotBytes);
  u16* slotP = (u16*)alloc(slotBytes);

  const void* u = d_in[0];

  k_detect<<<1, 1, 0, stream>>>(d_in[3], flag);
  {
    CvtTab t;
    int cum = 0;
    for (int i = 1; i < 28; ++i){
      t.src[i-1] = d_in[i];
      t.dst[i-1] = cin[i];
      t.cum[i-1] = cum;
      cum += in_sizes[i];
    }
    t.cum[27] = cum;
    k_cvtall<<<2048, 256, 0, stream>>>(t, flag, cum);
  }
  k_wprep<<<1024, 256, 0, stream>>>(cin[24], w1f, 8, 1024, 256*1024);
  k_wprep2<<<1024, 256, 0, stream>>>(cin[26], w2f);
  k_wtrans<<<512, 256, 0, stream>>>(cin[7],  WvT, 256, 512);   // to_v_w
  k_wtrans<<<512, 256, 0, stream>>>(cin[22], WmT, 512, 256);   // merge_w

  k_mod<<<24, 256, 0, stream>>>(cin[4], cin[5], cin[6], mod);
  k_lw<<<1, 128, 0, stream>>>(cin[1], lw);
  k_um2<<<NTOK/64, 256, 0, stream>>>(u, mod, um, flag);
  k_redx<<<1024, 256, 0, stream>>>(um, lw, redx);
  k_redy<<<512, 256, 0, stream>>>(um, redy);
  // bottleneck chains, x+y fused per stage
  gemm_row2<<<1536, 256, 0, stream>>>(redx, cin[8],  nullptr,  tx,  256, 256,
                                      redy, cin[13], nullptr,  ty,  256, 256, 1024, 0);
  gemm_row2<<<1536, 256, 0, stream>>>(tx,   cin[9],  cin[10],  hx,  256, 256,
                                      ty,   cin[14], cin[15],  hy,  256, 256, 1024, 1);
  gemm_row2<<<1536, 256, 0, stream>>>(hx,   cin[11], cin[12],  uxb, 256, 128,
                                      hy,   cin[16], cin[17],  uyb, 256, 128, 1024, 0);
  gemm_row2<<<1536, 256, 0, stream>>>(uxb,  cin[18], nullptr,  qkx, 128, 1024,
                                      uyb,  cin[19], nullptr,  qky, 128, 1024, 1024, 0);
  k_radial<<<(8*256*256)/256, 256, 0, stream>>>(cin[3], cin[20], radx, 256);
  k_radial<<<(8*128*128)/256, 256, 0, stream>>>(cin[2], cin[21], rady, 128);
  k_qkT<<<2048, 256, 0, stream>>>(qkx, kTx, 256);
  k_qkT<<<1024, 256, 0, stream>>>(qky, kTy, 128);
  k_attn2<<<4*8*256, 256, (64+8)*4, stream>>>(qkx, kTx, radx, kxb, 256);
  k_attn2<<<4*8*128, 128, (64+8)*4, stream>>>(qky, kTy, rady, kyb, 128);

  if (merged){
    // all 4 batches in flight; slotV/slotP hold [b][...] with stride SLOT_ELE
    k_v3    <<<2048, 256, 0, stream>>>(um, WvT, slotV, 0, SLOT_ELE);    // vA
    k_phi1c <<<2048, 256, 0, stream>>>(kyb, slotV, slotP, 0, SLOT_ELE); // phi
    k_phi2b <<<2048, 256, 0, stream>>>(kxb, slotP, slotV, 0, SLOT_ELE); // vA dead
    k_gnb   <<<8192, 256, 0, stream>>>(slotV, slotP, 0, SLOT_ELE);      // phi dead
    k_mergeb<<<1024, 256, 0, stream>>>(slotP, WmT, cin[23], mod, u, d_out, flag, 0, SLOT_ELE);
  } else {
    for (int b = 0; b < 4; ++b){
      k_v3    <<<512, 256, 0, stream>>>(um, WvT, slotV, b, 0);
      k_phi1c <<<512, 256, 0, stream>>>(kyb, slotV, slotP, b, 0);
      k_phi2b <<<512, 256, 0, stream>>>(kxb, slotP, slotV, b, 0);
      k_gnb   <<<2048, 256, 0, stream>>>(slotV, slotP, b, 0);
      k_mergeb<<<256, 256, 0, stream>>>(slotP, WmT, cin[23], mod, u, d_out, flag, b, 0);
    }
  }
  k_ffn4<<<NTOK/64, 256, 0, stream>>>(mod, w1f, cin[25], w2f, cin[27], d_out, flag);
}